// Round 3
// baseline (206.240 us; speedup 1.0000x reference)
//
#include <hip/hip_runtime.h>
#include <hip/hip_bf16.h>
#include <math.h>

// Problem constants
#define NB    4
#define NPTS  1024
#define DD    256
#define HWW   4096
#define NHEAD 8
#define DHD   32
#define NCHUNK 2
#define CHUNKK (HWW / NCHUNK)

typedef short s8v  __attribute__((ext_vector_type(8)));   // 8 x bf16 bits
typedef float f4v  __attribute__((ext_vector_type(4)));

#define MFMA_BF16 __builtin_amdgcn_mfma_f32_16x16x32_bf16

// -log(10000)/256
#define PE_FACT (-9.210340371976184f / 256.0f)
// log2(e)/sqrt(32) -- folded into Q so S-MFMA output is the exp2 argument
#define QSCALE 0.2550348637f

// LDS strides chosen so max bank aliasing is 2-way (free):
//   kt: 42 shorts/row (21 dw; 21*dc =? 4*dq mod 32 -> only dc=8,dq=2 -> 2-way)
//   vt: 69 dw/row     (5*dc  =? 4*dq mod 32 -> only dc=8,dq=2 -> 2-way)
//   plds: 138 shorts  (69 dw, same as vt)
#define KT_STRIDE 42
#define VT_STRIDE 69
#define PL_STRIDE 138

// ---------------------------------------------------------------------------
// K1: lf_pe = local_feat + pos_enc(32x32 grid); store fp32 (residual) + bf16
// ---------------------------------------------------------------------------
__global__ __launch_bounds__(256) void prep_local(const float* __restrict__ lf,
                                                  float* __restrict__ lf_pe_f32,
                                                  __hip_bfloat16* __restrict__ lf_pe_b) {
    int idx = blockIdx.x * 256 + threadIdx.x;      // < 4*1024*256
    int c = idx & 255;
    int p = (idx >> 8) & 1023;
    float div = __expf((float)(c & ~1) * PE_FACT);
    float pe;
    if (c & 1) {
        float y = (float)(p >> 5) * (1.0f / 31.0f);
        pe = __cosf(y * div);
    } else {
        float x = (float)(p & 31) * (1.0f / 31.0f);
        pe = __sinf(x * div);
    }
    float v = lf[idx] + pe;
    lf_pe_f32[idx] = v;
    lf_pe_b[idx] = __float2bfloat16(v);
}

// ---------------------------------------------------------------------------
// K2: gf_pe[n,p,c] = global_feat[n,c,p] + pos_enc(64x64 grid)  (LDS transpose)
// ---------------------------------------------------------------------------
__global__ __launch_bounds__(1024) void prep_global(const float* __restrict__ gfeat,
                                                    __hip_bfloat16* __restrict__ gf_pe_b) {
    __shared__ float tile[32][33];
    int n  = blockIdx.z;
    int p0 = blockIdx.x * 32;
    int c0 = blockIdx.y * 32;
    int tx = threadIdx.x, ty = threadIdx.y;
    tile[ty][tx] = gfeat[((size_t)n * DD + (c0 + ty)) * HWW + p0 + tx];
    __syncthreads();
    int p = p0 + ty, c = c0 + tx;
    float div = __expf((float)(c & ~1) * PE_FACT);
    float pe;
    if (c & 1) {
        float y = (float)(p >> 6) * (1.0f / 63.0f);
        pe = __cosf(y * div);
    } else {
        float x = (float)(p & 63) * (1.0f / 63.0f);
        pe = __sinf(x * div);
    }
    gf_pe_b[((size_t)n * HWW + p) * DD + c] = __float2bfloat16(tile[tx][ty] + pe);
}

// ---------------------------------------------------------------------------
// K3: weights -> bf16 (Wq | Wk | Wv | Wo packed consecutively)
// ---------------------------------------------------------------------------
__global__ __launch_bounds__(256) void w2b(const float* __restrict__ wq, const float* __restrict__ wk,
                                           const float* __restrict__ wv, const float* __restrict__ wo,
                                           __hip_bfloat16* __restrict__ out) {
    int idx = blockIdx.x * 256 + threadIdx.x;      // < 4*65536
    int m = idx >> 16, r = idx & 65535;
    const float* src = (m == 0) ? wq : (m == 1) ? wk : (m == 2) ? wv : wo;
    out[idx] = __float2bfloat16(src[r]);
}

// ---------------------------------------------------------------------------
// K4: GEMM  out = A(M,256) @ W^T(256,256) + bias  (register-prefetched K-loop)
//   MODE 0: Q  -> bf16 (n,h,NP,32), pre-scaled by QSCALE (exp2-ready scores)
//   MODE 3: fp32 (M,256) to d_out
// ---------------------------------------------------------------------------
template <int MODE>
__global__ __launch_bounds__(256) void gemm256(const __hip_bfloat16* __restrict__ A,
                                               const __hip_bfloat16* __restrict__ Wb,
                                               const float* __restrict__ bias,
                                               void* __restrict__ outp) {
    int wave = threadIdx.x >> 6;
    int lane = threadIdx.x & 63;
    int quad = lane >> 4, c16 = lane & 15;
    int m0 = blockIdx.x * 64 + wave * 16;
    int c0 = blockIdx.y * 64;
    const short* ap  = (const short*)A + (m0 + c16) * DD + quad * 8;
    const short* wp  = (const short*)Wb + (c0 + c16) * DD + quad * 8;

    f4v acc0 = {0.f, 0.f, 0.f, 0.f}, acc1 = acc0, acc2 = acc0, acc3 = acc0;

    s8v a  = *(const s8v*)(ap);
    s8v b0 = *(const s8v*)(wp);
    s8v b1 = *(const s8v*)(wp + 16 * DD);
    s8v b2 = *(const s8v*)(wp + 32 * DD);
    s8v b3 = *(const s8v*)(wp + 48 * DD);
#pragma unroll
    for (int ks = 0; ks < 8; ++ks) {
        s8v an, bn0, bn1, bn2, bn3;
        if (ks < 7) {
            int o = (ks + 1) * 32;
            an  = *(const s8v*)(ap + o);
            bn0 = *(const s8v*)(wp + o);
            bn1 = *(const s8v*)(wp + o + 16 * DD);
            bn2 = *(const s8v*)(wp + o + 32 * DD);
            bn3 = *(const s8v*)(wp + o + 48 * DD);
        }
        acc0 = MFMA_BF16(a, b0, acc0, 0, 0, 0);
        acc1 = MFMA_BF16(a, b1, acc1, 0, 0, 0);
        acc2 = MFMA_BF16(a, b2, acc2, 0, 0, 0);
        acc3 = MFMA_BF16(a, b3, acc3, 0, 0, 0);
        if (ks < 7) { a = an; b0 = bn0; b1 = bn1; b2 = bn2; b3 = bn3; }
    }
#pragma unroll
    for (int t = 0; t < 4; ++t) {
        f4v acc = (t == 0) ? acc0 : (t == 1) ? acc1 : (t == 2) ? acc2 : acc3;
        int col = c0 + t * 16 + c16;
        float bv = bias[col];
#pragma unroll
        for (int r = 0; r < 4; ++r) {
            int row = m0 + quad * 4 + r;
            float v = acc[r] + bv;
            if (MODE == 0) {            // Q: (n,h,NP,32), pre-scaled
                int n = row >> 10, p = row & 1023, h = col >> 5, dh = col & 31;
                ((__hip_bfloat16*)outp)[(((size_t)(n * NHEAD + h) << 10) + p) * DHD + dh] =
                    __float2bfloat16(v * QSCALE);
            } else {                    // fp32 out
                ((float*)outp)[(size_t)row * DD + col] = v;
            }
        }
    }
}

// ---------------------------------------------------------------------------
// K4b: fused K+V GEMM (register-prefetched): writes K and V in (n,h,HW,32)
// ---------------------------------------------------------------------------
__global__ __launch_bounds__(256) void gemmKV(const __hip_bfloat16* __restrict__ A,
                                              const __hip_bfloat16* __restrict__ Wk,
                                              const __hip_bfloat16* __restrict__ Wv,
                                              const float* __restrict__ bk,
                                              const float* __restrict__ bv,
                                              __hip_bfloat16* __restrict__ Kb,
                                              __hip_bfloat16* __restrict__ Vb) {
    int wave = threadIdx.x >> 6;
    int lane = threadIdx.x & 63;
    int quad = lane >> 4, c16 = lane & 15;
    int m0 = blockIdx.x * 64 + wave * 16;
    int c0 = blockIdx.y * 64;
    const short* ap  = (const short*)A + (m0 + c16) * DD + quad * 8;
    const short* wkp = (const short*)Wk + (c0 + c16) * DD + quad * 8;
    const short* wvp = (const short*)Wv + (c0 + c16) * DD + quad * 8;

    f4v ak0 = {0.f,0.f,0.f,0.f}, ak1 = ak0, ak2 = ak0, ak3 = ak0;
    f4v av0 = ak0, av1 = ak0, av2 = ak0, av3 = ak0;

    s8v a  = *(const s8v*)(ap);
    s8v k0 = *(const s8v*)(wkp);
    s8v k1 = *(const s8v*)(wkp + 16 * DD);
    s8v k2 = *(const s8v*)(wkp + 32 * DD);
    s8v k3 = *(const s8v*)(wkp + 48 * DD);
    s8v v0 = *(const s8v*)(wvp);
    s8v v1 = *(const s8v*)(wvp + 16 * DD);
    s8v v2 = *(const s8v*)(wvp + 32 * DD);
    s8v v3 = *(const s8v*)(wvp + 48 * DD);
#pragma unroll
    for (int ks = 0; ks < 8; ++ks) {
        s8v an, kn0, kn1, kn2, kn3, vn0, vn1, vn2, vn3;
        if (ks < 7) {
            int o = (ks + 1) * 32;
            an  = *(const s8v*)(ap + o);
            kn0 = *(const s8v*)(wkp + o);
            kn1 = *(const s8v*)(wkp + o + 16 * DD);
            kn2 = *(const s8v*)(wkp + o + 32 * DD);
            kn3 = *(const s8v*)(wkp + o + 48 * DD);
            vn0 = *(const s8v*)(wvp + o);
            vn1 = *(const s8v*)(wvp + o + 16 * DD);
            vn2 = *(const s8v*)(wvp + o + 32 * DD);
            vn3 = *(const s8v*)(wvp + o + 48 * DD);
        }
        ak0 = MFMA_BF16(a, k0, ak0, 0, 0, 0);
        ak1 = MFMA_BF16(a, k1, ak1, 0, 0, 0);
        ak2 = MFMA_BF16(a, k2, ak2, 0, 0, 0);
        ak3 = MFMA_BF16(a, k3, ak3, 0, 0, 0);
        av0 = MFMA_BF16(a, v0, av0, 0, 0, 0);
        av1 = MFMA_BF16(a, v1, av1, 0, 0, 0);
        av2 = MFMA_BF16(a, v2, av2, 0, 0, 0);
        av3 = MFMA_BF16(a, v3, av3, 0, 0, 0);
        if (ks < 7) {
            a = an; k0 = kn0; k1 = kn1; k2 = kn2; k3 = kn3;
            v0 = vn0; v1 = vn1; v2 = vn2; v3 = vn3;
        }
    }
#pragma unroll
    for (int t = 0; t < 4; ++t) {
        f4v accK = (t == 0) ? ak0 : (t == 1) ? ak1 : (t == 2) ? ak2 : ak3;
        f4v accV = (t == 0) ? av0 : (t == 1) ? av1 : (t == 2) ? av2 : av3;
        int col = c0 + t * 16 + c16;
        float bkv = bk[col], bvv = bv[col];
        int h = col >> 5, dh = col & 31;
#pragma unroll
        for (int r = 0; r < 4; ++r) {
            int row = m0 + quad * 4 + r;
            int n = row >> 12, p = row & 4095;
            size_t o = (((size_t)(n * NHEAD + h) << 12) + p) * DHD + dh;
            Kb[o] = __float2bfloat16(accK[r] + bkv);
            Vb[o] = __float2bfloat16(accV[r] + bvv);
        }
    }
}

// ---------------------------------------------------------------------------
// K5: attention partial, key-split NCHUNK, no-max exp2 softmax, KB=128.
//   flat grid 1024 = (8 xcd) x (8 groups) x (16 qtiles); group=(bh,chunk)
//   co-located per-XCD for K/V L2 reuse.
//   Writes UNNORMALIZED fp32 O-partials and row-sum partials.
// ---------------------------------------------------------------------------
__global__ __launch_bounds__(256) void attn(const __hip_bfloat16* __restrict__ Q,
                                            const __hip_bfloat16* __restrict__ Kg,
                                            const __hip_bfloat16* __restrict__ Vg,
                                            float* __restrict__ Opart,
                                            float* __restrict__ lpart) {
    __shared__ __align__(16) short kt[128 * KT_STRIDE];               // 10752 B
    __shared__ __align__(16) unsigned int vt[32 * VT_STRIDE];         //  8832 B
    __shared__ __align__(16) __hip_bfloat16 plds[4][16][PL_STRIDE];   // 17664 B

    int tid = threadIdx.x;
    int wave = tid >> 6, lane = tid & 63;
    int quad = lane >> 4, c16 = lane & 15;

    // swizzle: 16 q-tile blocks of a (bh,chunk) group share id%8 -> same XCD
    int id = blockIdx.x;
    int xcd = id & 7;
    int slot = id >> 3;
    int group = ((slot >> 4) << 3) | xcd;     // 0..63
    int qtile = slot & 15;
    int bh = group & 31;
    int chunk = group >> 5;
    int m0 = qtile * 64 + wave * 16;

    const short* Qs = (const short*)Q + (size_t)bh * NPTS * DHD;
    const short* Ks = (const short*)Kg + ((size_t)bh * HWW + chunk * CHUNKK) * DHD;
    const short* Vs = (const short*)Vg + ((size_t)bh * HWW + chunk * CHUNKK) * DHD;

    int skey = tid >> 1, shalf = (tid & 1) * 16;   // K staging
    int kp = tid & 63, dhg = tid >> 6;             // V staging

    s8v aq = *(const s8v*)(Qs + (m0 + c16) * DHD + quad * 8);

    // prologue: tile 0 into registers
    s8v kr0 = *(const s8v*)(Ks + (size_t)skey * DHD + shalf);
    s8v kr1 = *(const s8v*)(Ks + (size_t)skey * DHD + shalf + 8);
    s8v var = *(const s8v*)(Vs + (size_t)(2 * kp)     * DHD + dhg * 8);
    s8v vbr = *(const s8v*)(Vs + (size_t)(2 * kp + 1) * DHD + dhg * 8);

    f4v o0 = {0.f, 0.f, 0.f, 0.f}, o1 = {0.f, 0.f, 0.f, 0.f};
    const f4v zf = {0.f, 0.f, 0.f, 0.f};
    float lrow[4] = {0.f, 0.f, 0.f, 0.f};

    for (int j0 = 0; j0 < CHUNKK; j0 += 128) {
        __syncthreads();
        *(s8v*)&kt[skey * KT_STRIDE + shalf]     = kr0;
        *(s8v*)&kt[skey * KT_STRIDE + shalf + 8] = kr1;
#pragma unroll
        for (int i = 0; i < 8; ++i) {
            unsigned int lo = (unsigned short)var[i];
            unsigned int hi = (unsigned short)vbr[i];
            vt[(dhg * 8 + i) * VT_STRIDE + kp] = lo | (hi << 16);
        }
        __syncthreads();
        int jn = j0 + 128;
        if (jn < CHUNKK) {                 // prefetch next tile
            kr0 = *(const s8v*)(Ks + (size_t)(jn + skey) * DHD + shalf);
            kr1 = *(const s8v*)(Ks + (size_t)(jn + skey) * DHD + shalf + 8);
            var = *(const s8v*)(Vs + (size_t)(jn + 2 * kp)     * DHD + dhg * 8);
            vbr = *(const s8v*)(Vs + (size_t)(jn + 2 * kp + 1) * DHD + dhg * 8);
        }

        f4v s[8];
#pragma unroll
        for (int t = 0; t < 8; ++t) {
            s8v kb = *(const s8v*)&kt[(t * 16 + c16) * KT_STRIDE + quad * 8];
            s[t] = MFMA_BF16(aq, kb, zf, 0, 0, 0);
        }
#pragma unroll
        for (int r = 0; r < 4; ++r) {
            float ps = 0.f;
#pragma unroll
            for (int t = 0; t < 8; ++t) {
                float p = __builtin_amdgcn_exp2f(s[t][r]);
                ps += p;
                plds[wave][quad * 4 + r][t * 16 + c16] = __float2bfloat16(p);
            }
            lrow[r] += ps;
        }
#pragma unroll
        for (int tp = 0; tp < 4; ++tp) {
            s8v pa = *(const s8v*)&plds[wave][c16][tp * 32 + quad * 8];
            s8v vv0 = *(const s8v*)&vt[c16        * VT_STRIDE + tp * 16 + quad * 4];
            s8v vv1 = *(const s8v*)&vt[(16 + c16) * VT_STRIDE + tp * 16 + quad * 4];
            o0 = MFMA_BF16(pa, vv0, o0, 0, 0, 0);
            o1 = MFMA_BF16(pa, vv1, o1, 0, 0, 0);
        }
    }

    // epilogue: unnormalized partials
#pragma unroll
    for (int r = 0; r < 4; ++r) {
        float lr = lrow[r];
        lr += __shfl_xor(lr, 1, 16);
        lr += __shfl_xor(lr, 2, 16);
        lr += __shfl_xor(lr, 4, 16);
        lr += __shfl_xor(lr, 8, 16);
        int q = m0 + quad * 4 + r;
        size_t ob = (((size_t)(chunk * 32 + bh) << 10) + q) * DHD;
        Opart[ob + c16]      = o0[r];
        Opart[ob + 16 + c16] = o1[r];
        if (c16 == 0) lpart[((size_t)(chunk * 32 + bh) << 10) + q] = lr;
    }
}

// ---------------------------------------------------------------------------
// K6: combine chunks: AL = (O0+O1)/(l0+l1) + lf_pe  -> bf16 (n,p,256)
// ---------------------------------------------------------------------------
__global__ __launch_bounds__(256) void combine(const float* __restrict__ Opart,
                                               const float* __restrict__ lpart,
                                               const float* __restrict__ lf_pe,
                                               __hip_bfloat16* __restrict__ outb) {
    int idx = blockIdx.x * 256 + threadIdx.x;     // < 4*1024*256
    int c = idx & 255;
    int q = (idx >> 8) & 1023;
    int n = idx >> 18;
    int h = c >> 5, dh = c & 31;
    size_t bhq = ((size_t)(n * NHEAD + h) << 10) + q;
    float l = lpart[bhq] + lpart[bhq + (size_t)32 * NPTS];
    float o = Opart[bhq * DHD + dh] + Opart[(bhq + (size_t)32 * NPTS) * DHD + dh];
    outb[idx] = __float2bfloat16(o / l + lf_pe[idx]);
}

// ---------------------------------------------------------------------------
extern "C" void kernel_launch(void* const* d_in, const int* in_sizes, int n_in,
                              void* d_out, int out_size, void* d_ws, size_t ws_size,
                              hipStream_t stream) {
    const float* lf    = (const float*)d_in[0];
    const float* gfeat = (const float*)d_in[1];
    const float* Wq    = (const float*)d_in[2];
    const float* bq    = (const float*)d_in[3];
    const float* Wk    = (const float*)d_in[4];
    const float* bk    = (const float*)d_in[5];
    const float* Wv    = (const float*)d_in[6];
    const float* bv    = (const float*)d_in[7];
    const float* Wo    = (const float*)d_in[8];
    const float* bo    = (const float*)d_in[9];

    char* ws = (char*)d_ws;
    float*          lf_pe_f32 = (float*)(ws);                               // 0..4 MB
    float*          lpart     = (float*)(ws + (4u  << 20));                 // 4..4.25 MB (aliases lf_pe_b region after use)
    __hip_bfloat16* lf_pe_b   = (__hip_bfloat16*)(ws + (4u  << 20) + (512u << 10)); // 4.5..6.5 MB
    float*          Opart     = (float*)(ws + (66u << 20));                 // 66..74 MB
    __hip_bfloat16* gf_pe_b   = (__hip_bfloat16*)(ws + (7u  << 20));        // 7..15 MB
    __hip_bfloat16* W4        = (__hip_bfloat16*)(ws + (15u << 20));        // 0.5 MB
    __hip_bfloat16* Qb        = (__hip_bfloat16*)(ws + (16u << 20));        // 2 MB
    __hip_bfloat16* Kb        = (__hip_bfloat16*)(ws + (18u << 20));        // 8 MB
    __hip_bfloat16* Vb        = (__hip_bfloat16*)(ws + (26u << 20));        // 8 MB
    __hip_bfloat16* ALb       = (__hip_bfloat16*)(ws + (34u << 20));        // 2 MB
    // NOTE: if ws_size < 74 MB, fall back to aliasing Opart over gf_pe_b (dead
    // after gemmKV). Use the safe alias unconditionally:
    Opart = (float*)(ws + (7u << 20));   // aliases gf_pe_b: dead before attn writes

    prep_local<<<dim3(NB * NPTS * DD / 256), dim3(256), 0, stream>>>(lf, lf_pe_f32, lf_pe_b);
    prep_global<<<dim3(HWW / 32, DD / 32, NB), dim3(32, 32), 0, stream>>>(gfeat, gf_pe_b);
    w2b<<<dim3(4 * DD * DD / 256), dim3(256), 0, stream>>>(Wq, Wk, Wv, Wo, W4);

    gemm256<0><<<dim3(NB * NPTS / 64, 4), dim3(256), 0, stream>>>(lf_pe_b, W4, bq, (void*)Qb);
    gemmKV<<<dim3(NB * HWW / 64, 4), dim3(256), 0, stream>>>(gf_pe_b, W4 + 1 * DD * DD,
                                                             W4 + 2 * DD * DD, bk, bv, Kb, Vb);

    attn<<<dim3(16 * 32 * NCHUNK), dim3(256), 0, stream>>>(Qb, Kb, Vb, Opart, lpart);
    combine<<<dim3(NB * NPTS * DD / 256), dim3(256), 0, stream>>>(Opart, lpart, lf_pe_f32, ALb);

    gemm256<3><<<dim3(NB * NPTS / 64, 4), dim3(256), 0, stream>>>(ALb, W4 + 3 * DD * DD, bo, d_out);
}

// Round 4
// 182.407 us; speedup vs baseline: 1.1307x; 1.1307x over previous
//
#include <hip/hip_runtime.h>
#include <hip/hip_bf16.h>
#include <math.h>

// Problem constants
#define NB    4
#define NPTS  1024
#define DD    256
#define HWW   4096
#define NHEAD 8
#define DHD   32
#define VTROW 4128   // padded V^T row length in shorts (4096 + 32)

typedef short s8v  __attribute__((ext_vector_type(8)));   // 8 x bf16 bits
typedef float f4v  __attribute__((ext_vector_type(4)));
typedef unsigned int u2v __attribute__((ext_vector_type(2)));
typedef unsigned int u4v __attribute__((ext_vector_type(4)));

#define MFMA_BF16 __builtin_amdgcn_mfma_f32_16x16x32_bf16

// -log(10000)/256
#define PE_FACT (-9.210340371976184f / 256.0f)
// log2(e)/sqrt(32) -- folded into Q so S-MFMA output is the exp2 argument
#define QSCALE 0.2550348637f

#if defined(__has_builtin)
#if __has_builtin(__builtin_amdgcn_permlane16_swap) && __has_builtin(__builtin_amdgcn_permlane32_swap)
#define HAVE_PLSWAP 1
#endif
#endif

// pack two fp32 into one dword of bf16s (truncation): lo16=bf16(lo), hi16=bf16(hi)
__device__ __forceinline__ unsigned packbf(float hi, float lo) {
    return __builtin_amdgcn_perm(__float_as_uint(hi), __float_as_uint(lo), 0x07060302u);
}

// Given At = dword of P^T from S-MFMA over keys [base,base+16) (lane w holds keys 4w+{r,r+1})
// and Bt = same for keys [base+16,base+32), produce the two PV B-frag dwords:
//   x: dest lane (quad,c16) holds keys 8*quad+{2s,2s+1}   (wbase 0)
//   y: dest lane (quad,c16) holds keys 8*quad+{4+2s,5+2s}  (wbase 1)
__device__ __forceinline__ void swap2(unsigned a, unsigned b, unsigned& x, unsigned& y) {
#ifdef HAVE_PLSWAP
    u2v r1 = __builtin_amdgcn_permlane32_swap(a, b, false, false);
    u2v r2 = __builtin_amdgcn_permlane16_swap(r1.x, r1.y, false, false);
    x = r2.x; y = r2.y;
#else
    int l = threadIdx.x & 63;
    int i0 = ((((l >> 4) & 1) << 5) | (l & 15)) << 2;   // byte index for bpermute
    unsigned pa = (unsigned)__builtin_amdgcn_ds_bpermute(i0, (int)a);
    unsigned pb = (unsigned)__builtin_amdgcn_ds_bpermute(i0, (int)b);
    x = (l < 32) ? pa : pb;
    unsigned qa = (unsigned)__builtin_amdgcn_ds_bpermute(i0 + 64, (int)a);
    unsigned qb = (unsigned)__builtin_amdgcn_ds_bpermute(i0 + 64, (int)b);
    y = (l < 32) ? qa : qb;
#endif
}

// ---------------------------------------------------------------------------
// K1: lf_pe = local_feat + pos_enc(32x32 grid) -> bf16
// ---------------------------------------------------------------------------
__global__ __launch_bounds__(256) void prep_local(const float* __restrict__ lf,
                                                  __hip_bfloat16* __restrict__ lf_pe_b) {
    int idx = blockIdx.x * 256 + threadIdx.x;      // < 4*1024*256
    int c = idx & 255;
    int p = (idx >> 8) & 1023;
    float div = __expf((float)(c & ~1) * PE_FACT);
    float pe;
    if (c & 1) {
        float y = (float)(p >> 5) * (1.0f / 31.0f);
        pe = __cosf(y * div);
    } else {
        float x = (float)(p & 31) * (1.0f / 31.0f);
        pe = __sinf(x * div);
    }
    lf_pe_b[idx] = __float2bfloat16(lf[idx] + pe);
}

// ---------------------------------------------------------------------------
// K2: gf_pe[n,p,c] = global_feat[n,c,p] + pos_enc(64x64 grid)  (LDS transpose)
// ---------------------------------------------------------------------------
__global__ __launch_bounds__(1024) void prep_global(const float* __restrict__ gfeat,
                                                    __hip_bfloat16* __restrict__ gf_pe_b) {
    __shared__ float tile[32][33];
    int n  = blockIdx.z;
    int p0 = blockIdx.x * 32;
    int c0 = blockIdx.y * 32;
    int tx = threadIdx.x, ty = threadIdx.y;
    tile[ty][tx] = gfeat[((size_t)n * DD + (c0 + ty)) * HWW + p0 + tx];
    __syncthreads();
    int p = p0 + ty, c = c0 + tx;
    float div = __expf((float)(c & ~1) * PE_FACT);
    float pe;
    if (c & 1) {
        float y = (float)(p >> 6) * (1.0f / 63.0f);
        pe = __cosf(y * div);
    } else {
        float x = (float)(p & 63) * (1.0f / 63.0f);
        pe = __sinf(x * div);
    }
    gf_pe_b[((size_t)n * HWW + p) * DD + c] = __float2bfloat16(tile[tx][ty] + pe);
}

// ---------------------------------------------------------------------------
// K3: weights -> bf16 (Wq | Wk | Wv | Wo packed consecutively)
// ---------------------------------------------------------------------------
__global__ __launch_bounds__(256) void w2b(const float* __restrict__ wq, const float* __restrict__ wk,
                                           const float* __restrict__ wv, const float* __restrict__ wo,
                                           __hip_bfloat16* __restrict__ out) {
    int idx = blockIdx.x * 256 + threadIdx.x;      // < 4*65536
    int m = idx >> 16, r = idx & 65535;
    const float* src = (m == 0) ? wq : (m == 1) ? wk : (m == 2) ? wv : wo;
    out[idx] = __float2bfloat16(src[r]);
}

// ---------------------------------------------------------------------------
// K4: GEMM  out = A(M,256) @ W^T(256,256) + bias  (register-prefetched K-loop)
//   MODE 0: Q  -> bf16 (n,h,NP,32), pre-scaled by QSCALE (exp2-ready scores)
//   MODE 3: fp32 (M,256) to d_out
// ---------------------------------------------------------------------------
template <int MODE>
__global__ __launch_bounds__(256) void gemm256(const __hip_bfloat16* __restrict__ A,
                                               const __hip_bfloat16* __restrict__ Wb,
                                               const float* __restrict__ bias,
                                               void* __restrict__ outp) {
    int wave = threadIdx.x >> 6;
    int lane = threadIdx.x & 63;
    int quad = lane >> 4, c16 = lane & 15;
    int m0 = blockIdx.x * 64 + wave * 16;
    int c0 = blockIdx.y * 64;
    const short* ap  = (const short*)A + (m0 + c16) * DD + quad * 8;
    const short* wp  = (const short*)Wb + (c0 + c16) * DD + quad * 8;

    f4v acc0 = {0.f, 0.f, 0.f, 0.f}, acc1 = acc0, acc2 = acc0, acc3 = acc0;

    s8v a  = *(const s8v*)(ap);
    s8v b0 = *(const s8v*)(wp);
    s8v b1 = *(const s8v*)(wp + 16 * DD);
    s8v b2 = *(const s8v*)(wp + 32 * DD);
    s8v b3 = *(const s8v*)(wp + 48 * DD);
#pragma unroll
    for (int ks = 0; ks < 8; ++ks) {
        s8v an, bn0, bn1, bn2, bn3;
        if (ks < 7) {
            int o = (ks + 1) * 32;
            an  = *(const s8v*)(ap + o);
            bn0 = *(const s8v*)(wp + o);
            bn1 = *(const s8v*)(wp + o + 16 * DD);
            bn2 = *(const s8v*)(wp + o + 32 * DD);
            bn3 = *(const s8v*)(wp + o + 48 * DD);
        }
        acc0 = MFMA_BF16(a, b0, acc0, 0, 0, 0);
        acc1 = MFMA_BF16(a, b1, acc1, 0, 0, 0);
        acc2 = MFMA_BF16(a, b2, acc2, 0, 0, 0);
        acc3 = MFMA_BF16(a, b3, acc3, 0, 0, 0);
        if (ks < 7) { a = an; b0 = bn0; b1 = bn1; b2 = bn2; b3 = bn3; }
    }
#pragma unroll
    for (int t = 0; t < 4; ++t) {
        f4v acc = (t == 0) ? acc0 : (t == 1) ? acc1 : (t == 2) ? acc2 : acc3;
        int col = c0 + t * 16 + c16;
        float bv = bias[col];
#pragma unroll
        for (int r = 0; r < 4; ++r) {
            int row = m0 + quad * 4 + r;
            float v = acc[r] + bv;
            if (MODE == 0) {            // Q: (n,h,NP,32), pre-scaled
                int n = row >> 10, p = row & 1023, h = col >> 5, dh = col & 31;
                ((__hip_bfloat16*)outp)[(((size_t)(n * NHEAD + h) << 10) + p) * DHD + dh] =
                    __float2bfloat16(v * QSCALE);
            } else {                    // fp32 out
                ((float*)outp)[(size_t)row * DD + col] = v;
            }
        }
    }
}

// ---------------------------------------------------------------------------
// K4b: fused K+V GEMM: K -> (n,h,HW,32) bf16 (scatter, as before);
//      V -> TRANSPOSED (n,h,32,VTROW) bf16 via LDS bounce (coalesced stores)
// ---------------------------------------------------------------------------
__global__ __launch_bounds__(256) void gemmKV(const __hip_bfloat16* __restrict__ A,
                                              const __hip_bfloat16* __restrict__ Wk,
                                              const __hip_bfloat16* __restrict__ Wv,
                                              const float* __restrict__ bk,
                                              const float* __restrict__ bv,
                                              __hip_bfloat16* __restrict__ Kb,
                                              __hip_bfloat16* __restrict__ Vtb) {
    __shared__ __align__(16) unsigned stv[64][36];   // [col_local][key-pair dword], 9216 B

    int tid = threadIdx.x;
    int wave = tid >> 6;
    int lane = tid & 63;
    int quad = lane >> 4, c16 = lane & 15;
    int m0 = blockIdx.x * 64 + wave * 16;
    int c0 = blockIdx.y * 64;
    const short* ap  = (const short*)A + (m0 + c16) * DD + quad * 8;
    const short* wkp = (const short*)Wk + (c0 + c16) * DD + quad * 8;
    const short* wvp = (const short*)Wv + (c0 + c16) * DD + quad * 8;

    f4v ak0 = {0.f,0.f,0.f,0.f}, ak1 = ak0, ak2 = ak0, ak3 = ak0;
    f4v av0 = ak0, av1 = ak0, av2 = ak0, av3 = ak0;

    s8v a  = *(const s8v*)(ap);
    s8v k0 = *(const s8v*)(wkp);
    s8v k1 = *(const s8v*)(wkp + 16 * DD);
    s8v k2 = *(const s8v*)(wkp + 32 * DD);
    s8v k3 = *(const s8v*)(wkp + 48 * DD);
    s8v v0 = *(const s8v*)(wvp);
    s8v v1 = *(const s8v*)(wvp + 16 * DD);
    s8v v2 = *(const s8v*)(wvp + 32 * DD);
    s8v v3 = *(const s8v*)(wvp + 48 * DD);
#pragma unroll
    for (int ks = 0; ks < 8; ++ks) {
        s8v an, kn0, kn1, kn2, kn3, vn0, vn1, vn2, vn3;
        if (ks < 7) {
            int o = (ks + 1) * 32;
            an  = *(const s8v*)(ap + o);
            kn0 = *(const s8v*)(wkp + o);
            kn1 = *(const s8v*)(wkp + o + 16 * DD);
            kn2 = *(const s8v*)(wkp + o + 32 * DD);
            kn3 = *(const s8v*)(wkp + o + 48 * DD);
            vn0 = *(const s8v*)(wvp + o);
            vn1 = *(const s8v*)(wvp + o + 16 * DD);
            vn2 = *(const s8v*)(wvp + o + 32 * DD);
            vn3 = *(const s8v*)(wvp + o + 48 * DD);
        }
        ak0 = MFMA_BF16(a, k0, ak0, 0, 0, 0);
        ak1 = MFMA_BF16(a, k1, ak1, 0, 0, 0);
        ak2 = MFMA_BF16(a, k2, ak2, 0, 0, 0);
        ak3 = MFMA_BF16(a, k3, ak3, 0, 0, 0);
        av0 = MFMA_BF16(a, v0, av0, 0, 0, 0);
        av1 = MFMA_BF16(a, v1, av1, 0, 0, 0);
        av2 = MFMA_BF16(a, v2, av2, 0, 0, 0);
        av3 = MFMA_BF16(a, v3, av3, 0, 0, 0);
        if (ks < 7) {
            a = an; k0 = kn0; k1 = kn1; k2 = kn2; k3 = kn3;
            v0 = vn0; v1 = vn1; v2 = vn2; v3 = vn3;
        }
    }
    int nblk = (blockIdx.x * 64) >> 12;            // batch index (64 | 4096)
    int kb   = (blockIdx.x * 64) & 4095;           // key base within (n,h)
#pragma unroll
    for (int t = 0; t < 4; ++t) {
        f4v accK = (t == 0) ? ak0 : (t == 1) ? ak1 : (t == 2) ? ak2 : ak3;
        f4v accV = (t == 0) ? av0 : (t == 1) ? av1 : (t == 2) ? av2 : av3;
        int col = c0 + t * 16 + c16;
        float bkv = bk[col], bvv = bv[col];
        int h = col >> 5, dh = col & 31;
#pragma unroll
        for (int r = 0; r < 4; ++r) {
            int row = m0 + quad * 4 + r;
            int p = row & 4095;
            Kb[(((size_t)(nblk * NHEAD + h) << 12) + p) * DHD + dh] = __float2bfloat16(accK[r] + bkv);
        }
        // V: pack key-pairs -> LDS (transpose bounce)
#pragma unroll
        for (int rp = 0; rp < 2; ++rp) {
            __hip_bfloat16 lo = __float2bfloat16(accV[2 * rp] + bvv);
            __hip_bfloat16 hi = __float2bfloat16(accV[2 * rp + 1] + bvv);
            unsigned dw = (unsigned)*(unsigned short*)&lo | ((unsigned)*(unsigned short*)&hi << 16);
            stv[t * 16 + c16][wave * 8 + quad * 2 + rp] = dw;
        }
    }
    __syncthreads();
    // coalesced V^T store: thread -> (col, 16-key span)
    int col = tid >> 2;              // 0..63
    int kd  = (tid & 3) * 8;         // dword offset: 0,8,16,24
    u4v w0 = *(const u4v*)&stv[col][kd];
    u4v w1 = *(const u4v*)&stv[col][kd + 4];
    int gh  = (c0 + col) >> 5, gdh = (c0 + col) & 31;
    short* vp = (short*)Vtb + ((size_t)(nblk * NHEAD + gh) * DHD + gdh) * VTROW + kb + kd * 2;
    *(u4v*)(vp)     = w0;
    *(u4v*)(vp + 8) = w1;
}

// ---------------------------------------------------------------------------
// K5: attention partial. NO LDS, no barriers. 64 q-rows/wave (4 groups of 16).
//   S^T = K·Q^T via MFMA(A=K,B=Q) -> P^T in C-layout -> permlane-swap into
//   PV B-operand layout -> O^T = V^T·P^T. Unnormalized exp2 softmax.
//   grid: flat 128*NC blocks, XCD-swizzled so the 4 q-tile blocks of each
//   (bh,chunk) share an XCD (L2-resident K/V chunk).
//   Writes bf16 O-partials (chunk,bh,q,dh) + fp32 row-sums.
// ---------------------------------------------------------------------------
template <int NC>
__global__ __launch_bounds__(256) void attn(const __hip_bfloat16* __restrict__ Q,
                                            const __hip_bfloat16* __restrict__ Kg,
                                            const __hip_bfloat16* __restrict__ Vt,
                                            __hip_bfloat16* __restrict__ Opart,
                                            float* __restrict__ lpart) {
    constexpr int CK = HWW / NC;         // keys per chunk
    constexpr int NSTEP = CK / 32;       // 32-key steps

    int tid = threadIdx.x;
    int wave = tid >> 6, lane = tid & 63;
    int quad = lane >> 4, c16 = lane & 15;

    int id = blockIdx.x;
    int xcd = id & 7;
    int s = id >> 3;
    int qtile = s & 3;
    int gidx = ((s >> 2) << 3) | xcd;    // 0..32*NC-1
    int bh = gidx & 31;
    int chunk = gidx >> 5;

    int q0 = qtile * 256 + wave * 64;

    const short* Qs = (const short*)Q + (size_t)bh * NPTS * DHD;
    const short* Ks = (const short*)Kg + ((size_t)bh * HWW + (size_t)chunk * CK) * DHD;
    const short* Vs = (const short*)Vt + (size_t)bh * DHD * VTROW + (size_t)chunk * CK;

    s8v aq[4];
#pragma unroll
    for (int g = 0; g < 4; ++g)
        aq[g] = *(const s8v*)(Qs + (q0 + g * 16 + c16) * DHD + quad * 8);

    const f4v zf = {0.f, 0.f, 0.f, 0.f};
    f4v o[4][2];
#pragma unroll
    for (int g = 0; g < 4; ++g) { o[g][0] = zf; o[g][1] = zf; }
    float lsum[4] = {0.f, 0.f, 0.f, 0.f};

    const short* kbase  = Ks + c16 * DHD + quad * 8;
    const short* v0base = Vs + c16 * VTROW + quad * 8;
    const short* v1base = Vs + (16 + c16) * VTROW + quad * 8;

    s8v kfA = *(const s8v*)(kbase);
    s8v kfB = *(const s8v*)(kbase + 16 * DHD);
    s8v vfA = *(const s8v*)(v0base);
    s8v vfB = *(const s8v*)(v1base);

    for (int st = 0; st < NSTEP; ++st) {
        bool more = (st + 1) < NSTEP;
        s8v nkA, nkB, nvA, nvB;
        if (more) {
            int ko = (st + 1) * 32;
            nkA = *(const s8v*)(kbase + ko * DHD);
            nkB = *(const s8v*)(kbase + ko * DHD + 16 * DHD);
            nvA = *(const s8v*)(v0base + ko);
            nvB = *(const s8v*)(v1base + ko);
        }
#pragma unroll
        for (int g = 0; g < 4; ++g) {
            f4v sA = MFMA_BF16(kfA, aq[g], zf, 0, 0, 0);   // P^T keys [32st..+16)
            f4v sB = MFMA_BF16(kfB, aq[g], zf, 0, 0, 0);   // P^T keys [+16..+32)
            float pA0 = __builtin_amdgcn_exp2f(sA[0]);
            float pA1 = __builtin_amdgcn_exp2f(sA[1]);
            float pA2 = __builtin_amdgcn_exp2f(sA[2]);
            float pA3 = __builtin_amdgcn_exp2f(sA[3]);
            float pB0 = __builtin_amdgcn_exp2f(sB[0]);
            float pB1 = __builtin_amdgcn_exp2f(sB[1]);
            float pB2 = __builtin_amdgcn_exp2f(sB[2]);
            float pB3 = __builtin_amdgcn_exp2f(sB[3]);
            lsum[g] += ((pA0 + pA1) + (pA2 + pA3)) + ((pB0 + pB1) + (pB2 + pB3));
            unsigned a0 = packbf(pA1, pA0);   // r-pair (0,1)
            unsigned a1 = packbf(pA3, pA2);   // r-pair (2,3)
            unsigned b0 = packbf(pB1, pB0);
            unsigned b1 = packbf(pB3, pB2);
            unsigned x0, y0, x1, y1;
            swap2(a0, b0, x0, y0);            // j2 = 0, 2
            swap2(a1, b1, x1, y1);            // j2 = 1, 3
            union { u4v u; s8v s; } pf;
            pf.u = (u4v){x0, x1, y0, y1};     // B-frag: P^T[key=8q+j][qrow=c16]
            o[g][0] = MFMA_BF16(vfA, pf.s, o[g][0], 0, 0, 0);  // dh 0..15
            o[g][1] = MFMA_BF16(vfB, pf.s, o[g][1], 0, 0, 0);  // dh 16..31
        }
        if (more) { kfA = nkA; kfB = nkB; vfA = nvA; vfB = nvB; }
    }

    // epilogue: O^T lane holds dh=16h+4quad+r, q=q0+g*16+c16
    size_t obase = (size_t)(chunk * 32 + bh) * NPTS;
#pragma unroll
    for (int g = 0; g < 4; ++g) {
        float l = lsum[g];
        l += __shfl_xor(l, 16);
        l += __shfl_xor(l, 32);
        int q = q0 + g * 16 + c16;
        if (quad == 0) lpart[obase + q] = l;
        unsigned d0 = packbf(o[g][0][1], o[g][0][0]);
        unsigned d1 = packbf(o[g][0][3], o[g][0][2]);
        unsigned d2 = packbf(o[g][1][1], o[g][1][0]);
        unsigned d3 = packbf(o[g][1][3], o[g][1][2]);
        unsigned* op = (unsigned*)Opart + (obase + q) * (DHD / 2);
        *(u2v*)(op + 2 * quad)     = (u2v){d0, d1};   // dh 4quad..+3
        *(u2v*)(op + 8 + 2 * quad) = (u2v){d2, d3};   // dh 16+4quad..+3
    }
}

// ---------------------------------------------------------------------------
// K6: combine chunks: AL = (Σ O_ch)/(Σ l_ch) + lf_pe  -> bf16 (n,p,256)
// ---------------------------------------------------------------------------
template <int NC>
__global__ __launch_bounds__(256) void combine(const __hip_bfloat16* __restrict__ Opart,
                                               const float* __restrict__ lpart,
                                               const __hip_bfloat16* __restrict__ lf_pe,
                                               __hip_bfloat16* __restrict__ outb) {
    int idx = blockIdx.x * 256 + threadIdx.x;     // < 4*1024*256
    int c = idx & 255;
    int q = (idx >> 8) & 1023;
    int n = idx >> 18;
    int h = c >> 5, dh = c & 31;
    size_t bhq = ((size_t)(n * NHEAD + h) << 10) + q;
    float l = 0.f, o = 0.f;
#pragma unroll
    for (int ch = 0; ch < NC; ++ch) {
        l += lpart[(size_t)ch * 32 * NPTS + bhq];
        o += __bfloat162float(Opart[((size_t)ch * 32 * NPTS + bhq) * DHD + dh]);
    }
    outb[idx] = __float2bfloat16(o / l + __bfloat162float(lf_pe[idx]));
}

// ---------------------------------------------------------------------------
extern "C" void kernel_launch(void* const* d_in, const int* in_sizes, int n_in,
                              void* d_out, int out_size, void* d_ws, size_t ws_size,
                              hipStream_t stream) {
    const float* lf    = (const float*)d_in[0];
    const float* gfeat = (const float*)d_in[1];
    const float* Wq    = (const float*)d_in[2];
    const float* bq    = (const float*)d_in[3];
    const float* Wk    = (const float*)d_in[4];
    const float* bk    = (const float*)d_in[5];
    const float* Wv    = (const float*)d_in[6];
    const float* bv    = (const float*)d_in[7];
    const float* Wo    = (const float*)d_in[8];
    const float* bo    = (const float*)d_in[9];

    const size_t MB = 1u << 20;
    char* ws = (char*)d_ws;
    __hip_bfloat16* lf_pe_b = (__hip_bfloat16*)(ws);                      // 0..2 MB
    __hip_bfloat16* gf_pe_b = (__hip_bfloat16*)(ws + 2 * MB);             // 2..10 MB
    __hip_bfloat16* W4      = (__hip_bfloat16*)(ws + 10 * MB);            // 10..10.5 MB
    __hip_bfloat16* Qb      = (__hip_bfloat16*)(ws + 10 * MB + 512 * 1024); // 10.5..12.5
    __hip_bfloat16* Kb      = (__hip_bfloat16*)(ws + 12 * MB + 512 * 1024); // 12.5..20.5
    __hip_bfloat16* Vtb     = (__hip_bfloat16*)(ws + 20 * MB + 512 * 1024); // 20.5..29 (8.07 MB used)
    __hip_bfloat16* ALb     = (__hip_bfloat16*)(ws + 29 * MB);            // 29..31 MB
    float*          lpart   = (float*)(ws + 31 * MB);                     // 31..32 MB (<=1 MB)
    __hip_bfloat16* Opart   = (__hip_bfloat16*)(ws + 32 * MB);            // 32..32+NC*2 MB

    prep_local<<<dim3(NB * NPTS * DD / 256), dim3(256), 0, stream>>>(lf, lf_pe_b);
    prep_global<<<dim3(HWW / 32, DD / 32, NB), dim3(32, 32), 0, stream>>>(gfeat, gf_pe_b);
    w2b<<<dim3(4 * DD * DD / 256), dim3(256), 0, stream>>>(Wq, Wk, Wv, Wo, W4);

    gemm256<0><<<dim3(NB * NPTS / 64, 4), dim3(256), 0, stream>>>(lf_pe_b, W4, bq, (void*)Qb);
    gemmKV<<<dim3(NB * HWW / 64, 4), dim3(256), 0, stream>>>(gf_pe_b, W4 + 1 * DD * DD,
                                                             W4 + 2 * DD * DD, bk, bv, Kb, Vtb);

    // tier chunk count by available workspace (footprint = 32 MB + NC*2 MB)
    if (ws_size >= 48 * MB) {
        attn<8><<<dim3(128 * 8), dim3(256), 0, stream>>>(Qb, Kb, Vtb, Opart, lpart);
        combine<8><<<dim3(NB * NPTS * DD / 256), dim3(256), 0, stream>>>(Opart, lpart, lf_pe_b, ALb);
    } else if (ws_size >= 40 * MB) {
        attn<4><<<dim3(128 * 4), dim3(256), 0, stream>>>(Qb, Kb, Vtb, Opart, lpart);
        combine<4><<<dim3(NB * NPTS * DD / 256), dim3(256), 0, stream>>>(Opart, lpart, lf_pe_b, ALb);
    } else if (ws_size >= 36 * MB) {
        attn<2><<<dim3(128 * 2), dim3(256), 0, stream>>>(Qb, Kb, Vtb, Opart, lpart);
        combine<2><<<dim3(NB * NPTS * DD / 256), dim3(256), 0, stream>>>(Opart, lpart, lf_pe_b, ALb);
    } else {
        attn<1><<<dim3(128 * 1), dim3(256), 0, stream>>>(Qb, Kb, Vtb, Opart, lpart);
        combine<1><<<dim3(NB * NPTS * DD / 256), dim3(256), 0, stream>>>(Opart, lpart, lf_pe_b, ALb);
    }

    gemm256<3><<<dim3(NB * NPTS / 64, 4), dim3(256), 0, stream>>>(ALb, W4 + 3 * DD * DD, bo, d_out);
}

// Round 5
// 177.094 us; speedup vs baseline: 1.1646x; 1.0300x over previous
//
#include <hip/hip_runtime.h>
#include <hip/hip_bf16.h>
#include <math.h>

// Problem constants
#define NB    4
#define NPTS  1024
#define DD    256
#define HWW   4096
#define NHEAD 8
#define DHD   32
#define VTROW 4128   // padded V^T row length in shorts (4096 + 32)

typedef short s8v  __attribute__((ext_vector_type(8)));   // 8 x bf16 bits
typedef float f4v  __attribute__((ext_vector_type(4)));
typedef unsigned int u2v __attribute__((ext_vector_type(2)));
typedef unsigned int u4v __attribute__((ext_vector_type(4)));

#define MFMA_BF16 __builtin_amdgcn_mfma_f32_16x16x32_bf16

// -log(10000)/256
#define PE_FACT (-9.210340371976184f / 256.0f)
// log2(e)/sqrt(32) -- folded into Q so S-MFMA output is the exp2 argument
#define QSCALE 0.2550348637f

// pack two fp32 into one dword of bf16s (truncation): lo16=bf16(lo), hi16=bf16(hi)
__device__ __forceinline__ unsigned packbf(float hi, float lo) {
    return __builtin_amdgcn_perm(__float_as_uint(hi), __float_as_uint(lo), 0x07060302u);
}

// ---------------------------------------------------------------------------
// K1 (fused): blocks 0..4095   : lf_pe  = local_feat + pos_enc(32x32) -> bf16
//             blocks 4096..8191: gf_pe  = transpose(global_feat) + pos_enc(64x64)
//             blocks 8192..9215: weights -> bf16 (Wq|Wk|Wv|Wo)
// ---------------------------------------------------------------------------
__global__ __launch_bounds__(256) void prep(const float* __restrict__ lf,
                                            const float* __restrict__ gfeat,
                                            const float* __restrict__ wq,
                                            const float* __restrict__ wk,
                                            const float* __restrict__ wv,
                                            const float* __restrict__ wo,
                                            __hip_bfloat16* __restrict__ lf_pe_b,
                                            __hip_bfloat16* __restrict__ gf_pe_b,
                                            __hip_bfloat16* __restrict__ W4) {
    __shared__ float tile[32][33];
    int b = blockIdx.x, tid = threadIdx.x;
    if (b < 4096) {
        int idx = b * 256 + tid;
        int c = idx & 255, p = (idx >> 8) & 1023;
        float div = __expf((float)(c & ~1) * PE_FACT);
        float pe = (c & 1) ? __cosf((float)(p >> 5) * (1.0f / 31.0f) * div)
                           : __sinf((float)(p & 31) * (1.0f / 31.0f) * div);
        lf_pe_b[idx] = __float2bfloat16(lf[idx] + pe);
    } else if (b < 8192) {
        int t = b - 4096;
        int n = t >> 10, r = t & 1023;
        int p0 = (r >> 3) * 32, c0 = (r & 7) * 32;
        int tx = tid & 31, ty = tid >> 5;           // 32 x 8, 4 rows each
#pragma unroll
        for (int i = 0; i < 4; ++i)
            tile[ty + 8 * i][tx] = gfeat[((size_t)n * DD + (c0 + ty + 8 * i)) * HWW + p0 + tx];
        __syncthreads();
#pragma unroll
        for (int i = 0; i < 4; ++i) {
            int p = p0 + ty + 8 * i, c = c0 + tx;
            float div = __expf((float)(c & ~1) * PE_FACT);
            float pe = (c & 1) ? __cosf((float)(p >> 6) * (1.0f / 63.0f) * div)
                               : __sinf((float)(p & 63) * (1.0f / 63.0f) * div);
            gf_pe_b[((size_t)n * HWW + p) * DD + c] = __float2bfloat16(tile[tx][ty + 8 * i] + pe);
        }
    } else {
        int idx = (b - 8192) * 256 + tid;           // < 4*65536
        int m = idx >> 16, r = idx & 65535;
        const float* src = (m == 0) ? wq : (m == 1) ? wk : (m == 2) ? wv : wo;
        W4[idx] = __float2bfloat16(src[r]);
    }
}

// ---------------------------------------------------------------------------
// K2 (fused): blocks 0..255   : Q = lf_pe @ Wq^T + bq  -> bf16 (n,h,NP,32)*QSCALE
//             blocks 256..1279: K,V = gf_pe @ Wk^T/Wv^T + b
//               K -> (n,h,HW,32) bf16
//               V -> (n,h,32,VTROW) bf16 TRANSPOSED with sigma key order:
//                    within each 32-key block, mem position 8q+j holds key
//                    4q+j (j<4) / 16+4q+(j-4) (j>=4) -- matches attn's in-lane
//                    P-fragment so PV needs NO cross-lane transpose.
// ---------------------------------------------------------------------------
__global__ __launch_bounds__(256) void gemmQKV(const __hip_bfloat16* __restrict__ Aq,
                                               const __hip_bfloat16* __restrict__ Akv,
                                               const __hip_bfloat16* __restrict__ W4,
                                               const float* __restrict__ bq,
                                               const float* __restrict__ bk,
                                               const float* __restrict__ bv,
                                               __hip_bfloat16* __restrict__ Qb,
                                               __hip_bfloat16* __restrict__ Kb,
                                               __hip_bfloat16* __restrict__ Vtb) {
    __shared__ __align__(16) unsigned stv[64][36];
    int tid = threadIdx.x;
    int wave = tid >> 6, lane = tid & 63;
    int quad = lane >> 4, c16 = lane & 15;
    int b = blockIdx.x;

    if (b < 256) {   // ---- Q ----
        int m0 = (b & 63) * 64 + wave * 16;
        int c0 = (b >> 6) * 64;
        const short* ap = (const short*)Aq + (m0 + c16) * DD + quad * 8;
        const short* wp = (const short*)W4 + (c0 + c16) * DD + quad * 8;   // Wq @ 0
        f4v acc0 = {0.f,0.f,0.f,0.f}, acc1 = acc0, acc2 = acc0, acc3 = acc0;
#pragma unroll
        for (int ks = 0; ks < 8; ++ks) {
            int o = ks * 32;
            s8v a  = *(const s8v*)(ap + o);
            s8v b0 = *(const s8v*)(wp + o);
            s8v b1 = *(const s8v*)(wp + o + 16 * DD);
            s8v b2 = *(const s8v*)(wp + o + 32 * DD);
            s8v b3 = *(const s8v*)(wp + o + 48 * DD);
            acc0 = MFMA_BF16(a, b0, acc0, 0, 0, 0);
            acc1 = MFMA_BF16(a, b1, acc1, 0, 0, 0);
            acc2 = MFMA_BF16(a, b2, acc2, 0, 0, 0);
            acc3 = MFMA_BF16(a, b3, acc3, 0, 0, 0);
        }
#pragma unroll
        for (int t = 0; t < 4; ++t) {
            f4v acc = (t == 0) ? acc0 : (t == 1) ? acc1 : (t == 2) ? acc2 : acc3;
            int col = c0 + t * 16 + c16;
            float bvv = bq[col];
            int h = col >> 5, dh = col & 31;
#pragma unroll
            for (int r = 0; r < 4; ++r) {
                int row = m0 + quad * 4 + r;
                int n = row >> 10, p = row & 1023;
                Qb[(((size_t)(n * NHEAD + h) << 10) + p) * DHD + dh] =
                    __float2bfloat16((acc[r] + bvv) * QSCALE);
            }
        }
    } else {         // ---- K & V ----
        int b2 = b - 256;
        int mblk = b2 & 255;
        int m0 = mblk * 64 + wave * 16;
        int c0 = (b2 >> 8) * 64;
        const short* ap  = (const short*)Akv + (m0 + c16) * DD + quad * 8;
        const short* wkp = (const short*)W4 + DD * DD     + (c0 + c16) * DD + quad * 8;
        const short* wvp = (const short*)W4 + 2 * DD * DD + (c0 + c16) * DD + quad * 8;
        f4v ak0 = {0.f,0.f,0.f,0.f}, ak1 = ak0, ak2 = ak0, ak3 = ak0;
        f4v av0 = ak0, av1 = ak0, av2 = ak0, av3 = ak0;
#pragma unroll
        for (int ks = 0; ks < 8; ++ks) {
            int o = ks * 32;
            s8v a  = *(const s8v*)(ap + o);
            s8v k0 = *(const s8v*)(wkp + o);
            s8v k1 = *(const s8v*)(wkp + o + 16 * DD);
            s8v k2 = *(const s8v*)(wkp + o + 32 * DD);
            s8v k3 = *(const s8v*)(wkp + o + 48 * DD);
            ak0 = MFMA_BF16(a, k0, ak0, 0, 0, 0);
            ak1 = MFMA_BF16(a, k1, ak1, 0, 0, 0);
            ak2 = MFMA_BF16(a, k2, ak2, 0, 0, 0);
            ak3 = MFMA_BF16(a, k3, ak3, 0, 0, 0);
            s8v v0 = *(const s8v*)(wvp + o);
            s8v v1 = *(const s8v*)(wvp + o + 16 * DD);
            s8v v2 = *(const s8v*)(wvp + o + 32 * DD);
            s8v v3 = *(const s8v*)(wvp + o + 48 * DD);
            av0 = MFMA_BF16(a, v0, av0, 0, 0, 0);
            av1 = MFMA_BF16(a, v1, av1, 0, 0, 0);
            av2 = MFMA_BF16(a, v2, av2, 0, 0, 0);
            av3 = MFMA_BF16(a, v3, av3, 0, 0, 0);
        }
        int blkbase = mblk * 64;
        int nblk = blkbase >> 12;            // batch index
        int kb   = blkbase & 4095;           // key base within (n,h)
#pragma unroll
        for (int t = 0; t < 4; ++t) {
            f4v accK = (t == 0) ? ak0 : (t == 1) ? ak1 : (t == 2) ? ak2 : ak3;
            f4v accV = (t == 0) ? av0 : (t == 1) ? av1 : (t == 2) ? av2 : av3;
            int col = c0 + t * 16 + c16;
            float bkv = bk[col], bvv = bv[col];
            int h = col >> 5, dh = col & 31;
#pragma unroll
            for (int r = 0; r < 4; ++r) {
                int row = m0 + quad * 4 + r;
                int p = row & 4095;
                Kb[(((size_t)(nblk * NHEAD + h) << 12) + p) * DHD + dh] =
                    __float2bfloat16(accK[r] + bkv);
            }
            // V: pack key-pairs -> LDS (transpose bounce); stv[col][d]=keys(2d,2d+1)
#pragma unroll
            for (int rp = 0; rp < 2; ++rp) {
                __hip_bfloat16 lo = __float2bfloat16(accV[2 * rp] + bvv);
                __hip_bfloat16 hi = __float2bfloat16(accV[2 * rp + 1] + bvv);
                unsigned dw = (unsigned)*(unsigned short*)&lo | ((unsigned)*(unsigned short*)&hi << 16);
                stv[t * 16 + c16][wave * 8 + quad * 2 + rp] = dw;
            }
        }
        __syncthreads();
        // sigma-permuted coalesced V^T store
        int col = tid >> 2;              // 0..63
        int kd  = (tid & 3) * 8;         // out dword base (0,8,16,24)
        int grp = kd & 16;               // which 32-key group
        int ob  = kd & 15;
        unsigned vals[8];
#pragma unroll
        for (int i = 0; i < 8; ++i) {
            int o = ob + i;
            int idw = ((o >> 2) << 1) | (o & 1) | ((o & 2) << 2);  // inverse sigma, dword level
            vals[i] = stv[col][grp + idw];
        }
        u4v w0 = {vals[0], vals[1], vals[2], vals[3]};
        u4v w1 = {vals[4], vals[5], vals[6], vals[7]};
        int gh = (c0 + col) >> 5, gdh = (c0 + col) & 31;
        short* vp = (short*)Vtb + ((size_t)(nblk * NHEAD + gh) * DHD + gdh) * VTROW + kb + kd * 2;
        *(u4v*)(vp)     = w0;
        *(u4v*)(vp + 8) = w1;
    }
}

// ---------------------------------------------------------------------------
// K3: attention partial. NO LDS, no cross-lane. 64 q-rows/wave.
//   S^T = K.Q^T -> exp2 -> in-lane pack (keys sigma-ordered) -> O^T = V^T.P^T.
//   grid: flat 128*NC, XCD-swizzled; writes bf16 O-partials + fp32 row-sums.
// ---------------------------------------------------------------------------
template <int NC>
__global__ __launch_bounds__(256) void attn(const __hip_bfloat16* __restrict__ Q,
                                            const __hip_bfloat16* __restrict__ Kg,
                                            const __hip_bfloat16* __restrict__ Vt,
                                            __hip_bfloat16* __restrict__ Opart,
                                            float* __restrict__ lpart) {
    constexpr int CK = HWW / NC;         // keys per chunk
    constexpr int NSTEP = CK / 32;

    int tid = threadIdx.x;
    int wave = tid >> 6, lane = tid & 63;
    int quad = lane >> 4, c16 = lane & 15;

    int id = blockIdx.x;
    int xcd = id & 7;
    int s = id >> 3;
    int qtile = s & 3;
    int gidx = ((s >> 2) << 3) | xcd;    // 0..32*NC-1
    int bh = gidx & 31;
    int chunk = gidx >> 5;

    int q0 = qtile * 256 + wave * 64;

    const short* Qs = (const short*)Q + (size_t)bh * NPTS * DHD;
    const short* Ks = (const short*)Kg + ((size_t)bh * HWW + (size_t)chunk * CK) * DHD;
    const short* Vs = (const short*)Vt + (size_t)bh * DHD * VTROW + (size_t)chunk * CK;

    s8v aq[4];
#pragma unroll
    for (int g = 0; g < 4; ++g)
        aq[g] = *(const s8v*)(Qs + (q0 + g * 16 + c16) * DHD + quad * 8);

    const f4v zf = {0.f, 0.f, 0.f, 0.f};
    f4v o[4][2];
#pragma unroll
    for (int g = 0; g < 4; ++g) { o[g][0] = zf; o[g][1] = zf; }
    float lsum[4] = {0.f, 0.f, 0.f, 0.f};

    const short* kbase  = Ks + c16 * DHD + quad * 8;
    const short* v0base = Vs + c16 * VTROW + quad * 8;
    const short* v1base = Vs + (16 + c16) * VTROW + quad * 8;

    s8v kfA = *(const s8v*)(kbase);
    s8v kfB = *(const s8v*)(kbase + 16 * DHD);
    s8v vfA = *(const s8v*)(v0base);
    s8v vfB = *(const s8v*)(v1base);

    for (int st = 0; st < NSTEP; ++st) {
        bool more = (st + 1) < NSTEP;
        s8v nkA, nkB, nvA, nvB;
        if (more) {
            int ko = (st + 1) * 32;
            nkA = *(const s8v*)(kbase + ko * DHD);
            nkB = *(const s8v*)(kbase + ko * DHD + 16 * DHD);
            nvA = *(const s8v*)(v0base + ko);
            nvB = *(const s8v*)(v1base + ko);
        }
#pragma unroll
        for (int g = 0; g < 4; ++g) {
            f4v sA = MFMA_BF16(kfA, aq[g], zf, 0, 0, 0);   // P^T keys 4q+r
            f4v sB = MFMA_BF16(kfB, aq[g], zf, 0, 0, 0);   // P^T keys 16+4q+r
            float pA0 = __builtin_amdgcn_exp2f(sA[0]);
            float pA1 = __builtin_amdgcn_exp2f(sA[1]);
            float pA2 = __builtin_amdgcn_exp2f(sA[2]);
            float pA3 = __builtin_amdgcn_exp2f(sA[3]);
            float pB0 = __builtin_amdgcn_exp2f(sB[0]);
            float pB1 = __builtin_amdgcn_exp2f(sB[1]);
            float pB2 = __builtin_amdgcn_exp2f(sB[2]);
            float pB3 = __builtin_amdgcn_exp2f(sB[3]);
            lsum[g] += ((pA0 + pA1) + (pA2 + pA3)) + ((pB0 + pB1) + (pB2 + pB3));
            // B-frag directly (V^T is sigma-ordered): k=8q+j <-> {sA r0..3, sB r0..3}
            union { u4v u; s8v s; } pf;
            pf.u = (u4v){packbf(pA1, pA0), packbf(pA3, pA2),
                         packbf(pB1, pB0), packbf(pB3, pB2)};
            o[g][0] = MFMA_BF16(vfA, pf.s, o[g][0], 0, 0, 0);  // dh 0..15
            o[g][1] = MFMA_BF16(vfB, pf.s, o[g][1], 0, 0, 0);  // dh 16..31
        }
        if (more) { kfA = nkA; kfB = nkB; vfA = nvA; vfB = nvB; }
    }

    // epilogue: O^T lane holds dh=16*half+4quad+r, q=q0+g*16+c16
    size_t obase = (size_t)(chunk * 32 + bh) * NPTS;
#pragma unroll
    for (int g = 0; g < 4; ++g) {
        float l = lsum[g];
        l += __shfl_xor(l, 16);
        l += __shfl_xor(l, 32);
        int q = q0 + g * 16 + c16;
        if (quad == 0) lpart[obase + q] = l;
        unsigned d0 = packbf(o[g][0][1], o[g][0][0]);
        unsigned d1 = packbf(o[g][0][3], o[g][0][2]);
        unsigned d2 = packbf(o[g][1][1], o[g][1][0]);
        unsigned d3 = packbf(o[g][1][3], o[g][1][2]);
        unsigned* op = (unsigned*)Opart + (obase + q) * (DHD / 2);
        *(u2v*)(op + 2 * quad)     = (u2v){d0, d1};
        *(u2v*)(op + 8 + 2 * quad) = (u2v){d2, d3};
    }
}

// ---------------------------------------------------------------------------
// K4 (fused): combine chunks into AL tile in LDS, then output GEMM.
//   grid 128 blocks x 32 rows. AL = (sum O)/(sum l) + lf_pe; out = AL@Wo^T+bo.
// ---------------------------------------------------------------------------
template <int NC>
__global__ __launch_bounds__(256) void combineO(const __hip_bfloat16* __restrict__ Opart,
                                                const float* __restrict__ lpart,
                                                const __hip_bfloat16* __restrict__ lf_pe,
                                                const __hip_bfloat16* __restrict__ Wo4,
                                                const float* __restrict__ bo,
                                                float* __restrict__ out) {
    __shared__ __align__(16) short al[32][264];
    int tid = threadIdx.x;
    int m0 = blockIdx.x * 32;
    {   // phase 1: combine -> AL (bf16) in LDS. thread = (row, one 32-col h-seg)
        int rl = tid >> 3;            // 0..31
        int h  = tid & 7;
        int rg = m0 + rl;
        int n = rg >> 10, q = rg & 1023;
        size_t bhq = ((size_t)(n * NHEAD + h) << 10) + q;
        float l = 0.f;
        float ov[32];
#pragma unroll
        for (int d = 0; d < 32; ++d) ov[d] = 0.f;
#pragma unroll
        for (int ch = 0; ch < NC; ++ch) {
            size_t base = (size_t)ch * 32 * NPTS + bhq;
            l += lpart[base];
            const unsigned* op = (const unsigned*)((const short*)Opart + base * DHD);
#pragma unroll
            for (int dw = 0; dw < 16; ++dw) {
                unsigned u = op[dw];
                ov[2 * dw]     += __uint_as_float(u << 16);
                ov[2 * dw + 1] += __uint_as_float(u & 0xffff0000u);
            }
        }
        float linv = 1.0f / l;
        const unsigned* lp = (const unsigned*)((const short*)lf_pe + ((size_t)rg * DD + h * 32));
        unsigned* dst = (unsigned*)&al[rl][h * 32];
#pragma unroll
        for (int dw = 0; dw < 16; ++dw) {
            unsigned u = lp[dw];
            float x0 = ov[2 * dw] * linv     + __uint_as_float(u << 16);
            float x1 = ov[2 * dw + 1] * linv + __uint_as_float(u & 0xffff0000u);
            dst[dw] = packbf(x1, x0);
        }
    }
    __syncthreads();
    // phase 2: GEMM AL(32x256) @ Wo^T -> out rows m0..m0+31 (fp32)
    int wave = tid >> 6, lane = tid & 63;
    int quad = lane >> 4, c16 = lane & 15;
    int rw  = (wave & 1) * 16;
    int ch0 = (wave >> 1) * 128;
    f4v acc[8];
#pragma unroll
    for (int t = 0; t < 8; ++t) acc[t] = (f4v){0.f, 0.f, 0.f, 0.f};
#pragma unroll
    for (int ks = 0; ks < 8; ++ks) {
        s8v af = *(const s8v*)&al[rw + c16][ks * 32 + quad * 8];
#pragma unroll
        for (int t = 0; t < 8; ++t) {
            const short* wp = (const short*)Wo4 + (ch0 + t * 16 + c16) * DD + ks * 32 + quad * 8;
            s8v bf = *(const s8v*)wp;
            acc[t] = MFMA_BF16(af, bf, acc[t], 0, 0, 0);
        }
    }
#pragma unroll
    for (int t = 0; t < 8; ++t) {
        int col = ch0 + t * 16 + c16;
        float bv = bo[col];
#pragma unroll
        for (int r = 0; r < 4; ++r) {
            int row = m0 + rw + quad * 4 + r;
            out[(size_t)row * DD + col] = acc[t][r] + bv;
        }
    }
}

// ---------------------------------------------------------------------------
extern "C" void kernel_launch(void* const* d_in, const int* in_sizes, int n_in,
                              void* d_out, int out_size, void* d_ws, size_t ws_size,
                              hipStream_t stream) {
    const float* lf    = (const float*)d_in[0];
    const float* gfeat = (const float*)d_in[1];
    const float* Wq    = (const float*)d_in[2];
    const float* bq    = (const float*)d_in[3];
    const float* Wk    = (const float*)d_in[4];
    const float* bk    = (const float*)d_in[5];
    const float* Wv    = (const float*)d_in[6];
    const float* bv    = (const float*)d_in[7];
    const float* Wo    = (const float*)d_in[8];
    const float* bo    = (const float*)d_in[9];

    const size_t MB = 1u << 20;
    char* ws = (char*)d_ws;
    __hip_bfloat16* lf_pe_b = (__hip_bfloat16*)(ws);                          // 0..2 MB
    __hip_bfloat16* gf_pe_b = (__hip_bfloat16*)(ws + 2 * MB);                 // 2..10 MB
    __hip_bfloat16* W4      = (__hip_bfloat16*)(ws + 10 * MB);                // 10..10.5 MB
    __hip_bfloat16* Qb      = (__hip_bfloat16*)(ws + 10 * MB + 512 * 1024);   // 10.5..12.5
    __hip_bfloat16* Kb      = (__hip_bfloat16*)(ws + 12 * MB + 512 * 1024);   // 12.5..20.5
    __hip_bfloat16* Vtb     = (__hip_bfloat16*)(ws + 20 * MB + 512 * 1024);   // 20.5..29
    float*          lpart   = (float*)(ws + 31 * MB);                         // 31..32 MB
    __hip_bfloat16* Opart   = (__hip_bfloat16*)(ws + 32 * MB);                // 32..32+NC*2 MB

    prep<<<dim3(9216), dim3(256), 0, stream>>>(lf, gfeat, Wq, Wk, Wv, Wo,
                                               lf_pe_b, gf_pe_b, W4);
    gemmQKV<<<dim3(1280), dim3(256), 0, stream>>>(lf_pe_b, gf_pe_b, W4, bq, bk, bv,
                                                  Qb, Kb, Vtb);

    if (ws_size >= 48 * MB) {
        attn<8><<<dim3(128 * 8), dim3(256), 0, stream>>>(Qb, Kb, Vtb, Opart, lpart);
        combineO<8><<<dim3(128), dim3(256), 0, stream>>>(Opart, lpart, lf_pe_b,
                                                         W4 + 3 * DD * DD, bo, (float*)d_out);
    } else if (ws_size >= 40 * MB) {
        attn<4><<<dim3(128 * 4), dim3(256), 0, stream>>>(Qb, Kb, Vtb, Opart, lpart);
        combineO<4><<<dim3(128), dim3(256), 0, stream>>>(Opart, lpart, lf_pe_b,
                                                         W4 + 3 * DD * DD, bo, (float*)d_out);
    } else if (ws_size >= 36 * MB) {
        attn<2><<<dim3(128 * 2), dim3(256), 0, stream>>>(Qb, Kb, Vtb, Opart, lpart);
        combineO<2><<<dim3(128), dim3(256), 0, stream>>>(Opart, lpart, lf_pe_b,
                                                         W4 + 3 * DD * DD, bo, (float*)d_out);
    } else {
        attn<1><<<dim3(128 * 1), dim3(256), 0, stream>>>(Qb, Kb, Vtb, Opart, lpart);
        combineO<1><<<dim3(128), dim3(256), 0, stream>>>(Opart, lpart, lf_pe_b,
                                                         W4 + 3 * DD * DD, bo, (float*)d_out);
    }
}

// Round 6
// 168.674 us; speedup vs baseline: 1.2227x; 1.0499x over previous
//
#include <hip/hip_runtime.h>
#include <hip/hip_bf16.h>
#include <math.h>

// Problem constants
#define NB    4
#define NPTS  1024
#define DD    256
#define HWW   4096
#define NHEAD 8
#define DHD   32
#define VTROW 4128   // padded V^T row length in shorts (4096 + 32)

typedef short s8v  __attribute__((ext_vector_type(8)));   // 8 x bf16 bits
typedef float f4v  __attribute__((ext_vector_type(4)));
typedef unsigned int u2v __attribute__((ext_vector_type(2)));
typedef unsigned int u4v __attribute__((ext_vector_type(4)));

#define MFMA_BF16 __builtin_amdgcn_mfma_f32_16x16x32_bf16

// -log(10000)/256
#define PE_FACT (-9.210340371976184f / 256.0f)
// log2(e)/sqrt(32) -- folded into Q so S-MFMA output is the exp2 argument
#define QSCALE 0.2550348637f

// pack two fp32 into one dword of bf16s (truncation): lo16=bf16(lo), hi16=bf16(hi)
__device__ __forceinline__ unsigned packbf(float hi, float lo) {
    return __builtin_amdgcn_perm(__float_as_uint(hi), __float_as_uint(lo), 0x07060302u);
}

// ---------------------------------------------------------------------------
// K1 (fused): blocks 0..4095   : lf_pe  = local_feat + pos_enc(32x32) -> bf16
//             blocks 4096..8191: gf_pe  = transpose(global_feat) + pos_enc(64x64)
//             blocks 8192..9215: weights -> bf16 (Wq|Wk|Wv|Wo)
// ---------------------------------------------------------------------------
__global__ __launch_bounds__(256) void prep(const float* __restrict__ lf,
                                            const float* __restrict__ gfeat,
                                            const float* __restrict__ wq,
                                            const float* __restrict__ wk,
                                            const float* __restrict__ wv,
                                            const float* __restrict__ wo,
                                            __hip_bfloat16* __restrict__ lf_pe_b,
                                            __hip_bfloat16* __restrict__ gf_pe_b,
                                            __hip_bfloat16* __restrict__ W4) {
    __shared__ float tile[32][33];
    int b = blockIdx.x, tid = threadIdx.x;
    if (b < 4096) {
        int idx = b * 256 + tid;
        int c = idx & 255, p = (idx >> 8) & 1023;
        float div = __expf((float)(c & ~1) * PE_FACT);
        float pe = (c & 1) ? __cosf((float)(p >> 5) * (1.0f / 31.0f) * div)
                           : __sinf((float)(p & 31) * (1.0f / 31.0f) * div);
        lf_pe_b[idx] = __float2bfloat16(lf[idx] + pe);
    } else if (b < 8192) {
        int t = b - 4096;
        int n = t >> 10, r = t & 1023;
        int p0 = (r >> 3) * 32, c0 = (r & 7) * 32;
        int tx = tid & 31, ty = tid >> 5;           // 32 x 8, 4 rows each
#pragma unroll
        for (int i = 0; i < 4; ++i)
            tile[ty + 8 * i][tx] = gfeat[((size_t)n * DD + (c0 + ty + 8 * i)) * HWW + p0 + tx];
        __syncthreads();
#pragma unroll
        for (int i = 0; i < 4; ++i) {
            int p = p0 + ty + 8 * i, c = c0 + tx;
            float div = __expf((float)(c & ~1) * PE_FACT);
            float pe = (c & 1) ? __cosf((float)(p >> 6) * (1.0f / 63.0f) * div)
                               : __sinf((float)(p & 63) * (1.0f / 63.0f) * div);
            gf_pe_b[((size_t)n * HWW + p) * DD + c] = __float2bfloat16(tile[tx][ty + 8 * i] + pe);
        }
    } else {
        int idx = (b - 8192) * 256 + tid;           // < 4*65536
        int m = idx >> 16, r = idx & 65535;
        const float* src = (m == 0) ? wq : (m == 1) ? wk : (m == 2) ? wv : wo;
        W4[idx] = __float2bfloat16(src[r]);
    }
}

// ---------------------------------------------------------------------------
// K2: W-STATIONARY fused Q/K/V GEMM.
//   Each block owns one 64-column tile of one weight matrix, preloads its
//   W fragments into registers ONCE (32 x s8v), then loops over 2 m-tiles
//   of 64 rows, paying only 8 A-loads per 32 MFMAs per wave.
//   blocks 0..127    : Q  (4 col-tiles x 32 m-groups)  -> bf16 (n,h,NP,32)*QSCALE
//   blocks 128..1151 : K/V (8 combos x 128 m-groups)
//     K -> (n,h,HW,32) bf16
//     V -> (n,h,32,VTROW) bf16 transposed, sigma key order (in-lane P-frag match)
// ---------------------------------------------------------------------------
__global__ __launch_bounds__(256, 2) void gemmQKV(const __hip_bfloat16* __restrict__ Aq,
                                                  const __hip_bfloat16* __restrict__ Akv,
                                                  const __hip_bfloat16* __restrict__ W4,
                                                  const float* __restrict__ bq,
                                                  const float* __restrict__ bk,
                                                  const float* __restrict__ bv,
                                                  __hip_bfloat16* __restrict__ Qb,
                                                  __hip_bfloat16* __restrict__ Kb,
                                                  __hip_bfloat16* __restrict__ Vtb) {
    __shared__ __align__(16) unsigned stv[64][36];
    int tid = threadIdx.x;
    int wave = tid >> 6, lane = tid & 63;
    int quad = lane >> 4, c16 = lane & 15;
    int b = blockIdx.x;

    int typ, c0, mgrp, mstride;
    const short* Ap;
    const short* Wp;
    const float* bias;
    if (b < 128) {               // Q
        typ = 0; c0 = (b >> 5) * 64; mgrp = b & 31; mstride = 2048;
        Ap = (const short*)Aq; Wp = (const short*)W4; bias = bq;
    } else {                     // K or V
        int bb = b - 128;
        int combo = bb >> 7;     // 0..7
        mgrp = bb & 127; mstride = 8192;
        int mat = combo & 1;
        typ = 1 + mat;
        c0 = (combo >> 1) * 64;
        Ap = (const short*)Akv;
        Wp = (const short*)W4 + (1 + mat) * DD * DD;
        bias = mat ? bv : bk;
    }

    // ---- preload W fragments (32 x s8v = 128 VGPR) + bias ----
    s8v w[8][4];
    const short* wp0 = Wp + (c0 + c16) * DD + quad * 8;
#pragma unroll
    for (int ks = 0; ks < 8; ++ks)
#pragma unroll
        for (int t = 0; t < 4; ++t)
            w[ks][t] = *(const s8v*)(wp0 + t * 16 * DD + ks * 32);
    float bvv[4];
#pragma unroll
    for (int t = 0; t < 4; ++t) bvv[t] = bias[c0 + t * 16 + c16];

    // ---- m-tile loop ----
#pragma unroll
    for (int it = 0; it < 2; ++it) {
        int mbase = mgrp * 64 + it * mstride;        // block's 64-row tile base
        int m0 = mbase + wave * 16;
        const short* ap = Ap + (m0 + c16) * DD + quad * 8;
        s8v a[8];
#pragma unroll
        for (int ks = 0; ks < 8; ++ks) a[ks] = *(const s8v*)(ap + ks * 32);

        f4v acc[4];
#pragma unroll
        for (int t = 0; t < 4; ++t) acc[t] = (f4v){0.f, 0.f, 0.f, 0.f};
#pragma unroll
        for (int ks = 0; ks < 8; ++ks) {
#pragma unroll
            for (int t = 0; t < 4; ++t)
                acc[t] = MFMA_BF16(a[ks], w[ks][t], acc[t], 0, 0, 0);
        }

        if (typ == 0) {          // ---- Q store ----
#pragma unroll
            for (int t = 0; t < 4; ++t) {
                int col = c0 + t * 16 + c16;
                int h = col >> 5, dh = col & 31;
#pragma unroll
                for (int r = 0; r < 4; ++r) {
                    int row = m0 + quad * 4 + r;
                    int n = row >> 10, p = row & 1023;
                    Qb[(((size_t)(n * NHEAD + h) << 10) + p) * DHD + dh] =
                        __float2bfloat16((acc[t][r] + bvv[t]) * QSCALE);
                }
            }
        } else if (typ == 1) {   // ---- K store ----
#pragma unroll
            for (int t = 0; t < 4; ++t) {
                int col = c0 + t * 16 + c16;
                int h = col >> 5, dh = col & 31;
#pragma unroll
                for (int r = 0; r < 4; ++r) {
                    int row = m0 + quad * 4 + r;
                    int n = row >> 12, p = row & 4095;
                    Kb[(((size_t)(n * NHEAD + h) << 12) + p) * DHD + dh] =
                        __float2bfloat16(acc[t][r] + bvv[t]);
                }
            }
        } else {                 // ---- V: sigma-permuted transpose bounce ----
            __syncthreads();     // protect stv from previous iteration's readers
#pragma unroll
            for (int t = 0; t < 4; ++t) {
#pragma unroll
                for (int rp = 0; rp < 2; ++rp) {
                    __hip_bfloat16 lo = __float2bfloat16(acc[t][2 * rp] + bvv[t]);
                    __hip_bfloat16 hi = __float2bfloat16(acc[t][2 * rp + 1] + bvv[t]);
                    unsigned dw = (unsigned)*(unsigned short*)&lo |
                                  ((unsigned)*(unsigned short*)&hi << 16);
                    stv[t * 16 + c16][wave * 8 + quad * 2 + rp] = dw;
                }
            }
            __syncthreads();
            int col = tid >> 2;              // 0..63
            int kd  = (tid & 3) * 8;         // out dword base (0,8,16,24)
            int grp = kd & 16;
            int ob  = kd & 15;
            unsigned vals[8];
#pragma unroll
            for (int i = 0; i < 8; ++i) {
                int o = ob + i;
                int idw = ((o >> 2) << 1) | (o & 1) | ((o & 2) << 2);  // inverse sigma
                vals[i] = stv[col][grp + idw];
            }
            int nblk = mbase >> 12;
            int kb   = mbase & 4095;
            int gh = (c0 + col) >> 5, gdh = (c0 + col) & 31;
            short* vp = (short*)Vtb + ((size_t)(nblk * NHEAD + gh) * DHD + gdh) * VTROW + kb + kd * 2;
            *(u4v*)(vp)     = (u4v){vals[0], vals[1], vals[2], vals[3]};
            *(u4v*)(vp + 8) = (u4v){vals[4], vals[5], vals[6], vals[7]};
        }
    }
}

// ---------------------------------------------------------------------------
// K3: attention partial. NO LDS, no cross-lane. 64 q-rows/wave.
//   S^T = K.Q^T -> exp2 -> in-lane pack (keys sigma-ordered) -> O^T = V^T.P^T.
//   grid: flat 128*NC, XCD-swizzled; writes bf16 O-partials + fp32 row-sums.
// ---------------------------------------------------------------------------
template <int NC>
__global__ __launch_bounds__(256) void attn(const __hip_bfloat16* __restrict__ Q,
                                            const __hip_bfloat16* __restrict__ Kg,
                                            const __hip_bfloat16* __restrict__ Vt,
                                            __hip_bfloat16* __restrict__ Opart,
                                            float* __restrict__ lpart) {
    constexpr int CK = HWW / NC;         // keys per chunk
    constexpr int NSTEP = CK / 32;

    int tid = threadIdx.x;
    int wave = tid >> 6, lane = tid & 63;
    int quad = lane >> 4, c16 = lane & 15;

    int id = blockIdx.x;
    int xcd = id & 7;
    int s = id >> 3;
    int qtile = s & 3;
    int gidx = ((s >> 2) << 3) | xcd;    // 0..32*NC-1
    int bh = gidx & 31;
    int chunk = gidx >> 5;

    int q0 = qtile * 256 + wave * 64;

    const short* Qs = (const short*)Q + (size_t)bh * NPTS * DHD;
    const short* Ks = (const short*)Kg + ((size_t)bh * HWW + (size_t)chunk * CK) * DHD;
    const short* Vs = (const short*)Vt + (size_t)bh * DHD * VTROW + (size_t)chunk * CK;

    s8v aq[4];
#pragma unroll
    for (int g = 0; g < 4; ++g)
        aq[g] = *(const s8v*)(Qs + (q0 + g * 16 + c16) * DHD + quad * 8);

    const f4v zf = {0.f, 0.f, 0.f, 0.f};
    f4v o[4][2];
#pragma unroll
    for (int g = 0; g < 4; ++g) { o[g][0] = zf; o[g][1] = zf; }
    float lsum[4] = {0.f, 0.f, 0.f, 0.f};

    const short* kbase  = Ks + c16 * DHD + quad * 8;
    const short* v0base = Vs + c16 * VTROW + quad * 8;
    const short* v1base = Vs + (16 + c16) * VTROW + quad * 8;

    s8v kfA = *(const s8v*)(kbase);
    s8v kfB = *(const s8v*)(kbase + 16 * DHD);
    s8v vfA = *(const s8v*)(v0base);
    s8v vfB = *(const s8v*)(v1base);

    for (int st = 0; st < NSTEP; ++st) {
        bool more = (st + 1) < NSTEP;
        s8v nkA, nkB, nvA, nvB;
        if (more) {
            int ko = (st + 1) * 32;
            nkA = *(const s8v*)(kbase + ko * DHD);
            nkB = *(const s8v*)(kbase + ko * DHD + 16 * DHD);
            nvA = *(const s8v*)(v0base + ko);
            nvB = *(const s8v*)(v1base + ko);
        }
#pragma unroll
        for (int g = 0; g < 4; ++g) {
            f4v sA = MFMA_BF16(kfA, aq[g], zf, 0, 0, 0);   // P^T keys 4q+r
            f4v sB = MFMA_BF16(kfB, aq[g], zf, 0, 0, 0);   // P^T keys 16+4q+r
            float pA0 = __builtin_amdgcn_exp2f(sA[0]);
            float pA1 = __builtin_amdgcn_exp2f(sA[1]);
            float pA2 = __builtin_amdgcn_exp2f(sA[2]);
            float pA3 = __builtin_amdgcn_exp2f(sA[3]);
            float pB0 = __builtin_amdgcn_exp2f(sB[0]);
            float pB1 = __builtin_amdgcn_exp2f(sB[1]);
            float pB2 = __builtin_amdgcn_exp2f(sB[2]);
            float pB3 = __builtin_amdgcn_exp2f(sB[3]);
            lsum[g] += ((pA0 + pA1) + (pA2 + pA3)) + ((pB0 + pB1) + (pB2 + pB3));
            // B-frag directly (V^T is sigma-ordered): k=8q+j <-> {sA r0..3, sB r0..3}
            union { u4v u; s8v s; } pf;
            pf.u = (u4v){packbf(pA1, pA0), packbf(pA3, pA2),
                         packbf(pB1, pB0), packbf(pB3, pB2)};
            o[g][0] = MFMA_BF16(vfA, pf.s, o[g][0], 0, 0, 0);  // dh 0..15
            o[g][1] = MFMA_BF16(vfB, pf.s, o[g][1], 0, 0, 0);  // dh 16..31
        }
        if (more) { kfA = nkA; kfB = nkB; vfA = nvA; vfB = nvB; }
    }

    // epilogue: O^T lane holds dh=16*half+4quad+r, q=q0+g*16+c16
    size_t obase = (size_t)(chunk * 32 + bh) * NPTS;
#pragma unroll
    for (int g = 0; g < 4; ++g) {
        float l = lsum[g];
        l += __shfl_xor(l, 16);
        l += __shfl_xor(l, 32);
        int q = q0 + g * 16 + c16;
        if (quad == 0) lpart[obase + q] = l;
        unsigned d0 = packbf(o[g][0][1], o[g][0][0]);
        unsigned d1 = packbf(o[g][0][3], o[g][0][2]);
        unsigned d2 = packbf(o[g][1][1], o[g][1][0]);
        unsigned d3 = packbf(o[g][1][3], o[g][1][2]);
        unsigned* op = (unsigned*)Opart + (obase + q) * (DHD / 2);
        *(u2v*)(op + 2 * quad)     = (u2v){d0, d1};
        *(u2v*)(op + 8 + 2 * quad) = (u2v){d2, d3};
    }
}

// ---------------------------------------------------------------------------
// K4 (fused): combine chunks into AL tile in LDS, then output GEMM.
//   grid 128 blocks x 32 rows. AL = (sum O)/(sum l) + lf_pe; out = AL@Wo^T+bo.
// ---------------------------------------------------------------------------
template <int NC>
__global__ __launch_bounds__(256) void combineO(const __hip_bfloat16* __restrict__ Opart,
                                                const float* __restrict__ lpart,
                                                const __hip_bfloat16* __restrict__ lf_pe,
                                                const __hip_bfloat16* __restrict__ Wo4,
                                                const float* __restrict__ bo,
                                                float* __restrict__ out) {
    __shared__ __align__(16) short al[32][264];
    int tid = threadIdx.x;
    int m0 = blockIdx.x * 32;
    {   // phase 1: combine -> AL (bf16) in LDS. thread = (row, one 32-col h-seg)
        int rl = tid >> 3;            // 0..31
        int h  = tid & 7;
        int rg = m0 + rl;
        int n = rg >> 10, q = rg & 1023;
        size_t bhq = ((size_t)(n * NHEAD + h) << 10) + q;
        float l = 0.f;
        float ov[32];
#pragma unroll
        for (int d = 0; d < 32; ++d) ov[d] = 0.f;
#pragma unroll
        for (int ch = 0; ch < NC; ++ch) {
            size_t base = (size_t)ch * 32 * NPTS + bhq;
            l += lpart[base];
            const unsigned* op = (const unsigned*)((const short*)Opart + base * DHD);
#pragma unroll
            for (int dw = 0; dw < 16; ++dw) {
                unsigned u = op[dw];
                ov[2 * dw]     += __uint_as_float(u << 16);
                ov[2 * dw + 1] += __uint_as_float(u & 0xffff0000u);
            }
        }
        float linv = 1.0f / l;
        const unsigned* lp = (const unsigned*)((const short*)lf_pe + ((size_t)rg * DD + h * 32));
        unsigned* dst = (unsigned*)&al[rl][h * 32];
#pragma unroll
        for (int dw = 0; dw < 16; ++dw) {
            unsigned u = lp[dw];
            float x0 = ov[2 * dw] * linv     + __uint_as_float(u << 16);
            float x1 = ov[2 * dw + 1] * linv + __uint_as_float(u & 0xffff0000u);
            dst[dw] = packbf(x1, x0);
        }
    }
    __syncthreads();
    // phase 2: GEMM AL(32x256) @ Wo^T -> out rows m0..m0+31 (fp32)
    int wave = tid >> 6, lane = tid & 63;
    int quad = lane >> 4, c16 = lane & 15;
    int rw  = (wave & 1) * 16;
    int ch0 = (wave >> 1) * 128;
    f4v acc[8];
#pragma unroll
    for (int t = 0; t < 8; ++t) acc[t] = (f4v){0.f, 0.f, 0.f, 0.f};
#pragma unroll
    for (int ks = 0; ks < 8; ++ks) {
        s8v af = *(const s8v*)&al[rw + c16][ks * 32 + quad * 8];
#pragma unroll
        for (int t = 0; t < 8; ++t) {
            const short* wp = (const short*)Wo4 + (ch0 + t * 16 + c16) * DD + ks * 32 + quad * 8;
            s8v bf = *(const s8v*)wp;
            acc[t] = MFMA_BF16(af, bf, acc[t], 0, 0, 0);
        }
    }
#pragma unroll
    for (int t = 0; t < 8; ++t) {
        int col = ch0 + t * 16 + c16;
        float bv = bo[col];
#pragma unroll
        for (int r = 0; r < 4; ++r) {
            int row = m0 + rw + quad * 4 + r;
            out[(size_t)row * DD + col] = acc[t][r] + bv;
        }
    }
}

// ---------------------------------------------------------------------------
extern "C" void kernel_launch(void* const* d_in, const int* in_sizes, int n_in,
                              void* d_out, int out_size, void* d_ws, size_t ws_size,
                              hipStream_t stream) {
    const float* lf    = (const float*)d_in[0];
    const float* gfeat = (const float*)d_in[1];
    const float* Wq    = (const float*)d_in[2];
    const float* bq    = (const float*)d_in[3];
    const float* Wk    = (const float*)d_in[4];
    const float* bk    = (const float*)d_in[5];
    const float* Wv    = (const float*)d_in[6];
    const float* bv    = (const float*)d_in[7];
    const float* Wo    = (const float*)d_in[8];
    const float* bo    = (const float*)d_in[9];

    const size_t MB = 1u << 20;
    char* ws = (char*)d_ws;
    __hip_bfloat16* lf_pe_b = (__hip_bfloat16*)(ws);                          // 0..2 MB
    __hip_bfloat16* gf_pe_b = (__hip_bfloat16*)(ws + 2 * MB);                 // 2..10 MB
    __hip_bfloat16* W4      = (__hip_bfloat16*)(ws + 10 * MB);                // 10..10.5 MB
    __hip_bfloat16* Qb      = (__hip_bfloat16*)(ws + 10 * MB + 512 * 1024);   // 10.5..12.5
    __hip_bfloat16* Kb      = (__hip_bfloat16*)(ws + 12 * MB + 512 * 1024);   // 12.5..20.5
    __hip_bfloat16* Vtb     = (__hip_bfloat16*)(ws + 20 * MB + 512 * 1024);   // 20.5..29
    float*          lpart   = (float*)(ws + 31 * MB);                         // 31..32 MB
    __hip_bfloat16* Opart   = (__hip_bfloat16*)(ws + 32 * MB);                // 32..32+NC*2 MB

    prep<<<dim3(9216), dim3(256), 0, stream>>>(lf, gfeat, Wq, Wk, Wv, Wo,
                                               lf_pe_b, gf_pe_b, W4);
    gemmQKV<<<dim3(1152), dim3(256), 0, stream>>>(lf_pe_b, gf_pe_b, W4, bq, bk, bv,
                                                  Qb, Kb, Vtb);

    if (ws_size >= 48 * MB) {
        attn<8><<<dim3(128 * 8), dim3(256), 0, stream>>>(Qb, Kb, Vtb, Opart, lpart);
        combineO<8><<<dim3(128), dim3(256), 0, stream>>>(Opart, lpart, lf_pe_b,
                                                         W4 + 3 * DD * DD, bo, (float*)d_out);
    } else if (ws_size >= 40 * MB) {
        attn<4><<<dim3(128 * 4), dim3(256), 0, stream>>>(Qb, Kb, Vtb, Opart, lpart);
        combineO<4><<<dim3(128), dim3(256), 0, stream>>>(Opart, lpart, lf_pe_b,
                                                         W4 + 3 * DD * DD, bo, (float*)d_out);
    } else if (ws_size >= 36 * MB) {
        attn<2><<<dim3(128 * 2), dim3(256), 0, stream>>>(Qb, Kb, Vtb, Opart, lpart);
        combineO<2><<<dim3(128), dim3(256), 0, stream>>>(Opart, lpart, lf_pe_b,
                                                         W4 + 3 * DD * DD, bo, (float*)d_out);
    } else {
        attn<1><<<dim3(128 * 1), dim3(256), 0, stream>>>(Qb, Kb, Vtb, Opart, lpart);
        combineO<1><<<dim3(128), dim3(256), 0, stream>>>(Opart, lpart, lf_pe_b,
                                                         W4 + 3 * DD * DD, bo, (float*)d_out);
    }
}

// Round 7
// 161.714 us; speedup vs baseline: 1.2753x; 1.0430x over previous
//
#include <hip/hip_runtime.h>
#include <hip/hip_bf16.h>
#include <math.h>

// Problem constants
#define NB    4
#define NPTS  1024
#define DD    256
#define HWW   4096
#define NHEAD 8
#define DHD   32
#define VTROW 4128   // padded V^T row length in shorts (4096 + 32)

typedef short s8v  __attribute__((ext_vector_type(8)));   // 8 x bf16 bits
typedef float f4v  __attribute__((ext_vector_type(4)));
typedef unsigned int u2v __attribute__((ext_vector_type(2)));
typedef unsigned int u4v __attribute__((ext_vector_type(4)));

#define MFMA_BF16 __builtin_amdgcn_mfma_f32_16x16x32_bf16

// -log(10000)/256
#define PE_FACT (-9.210340371976184f / 256.0f)
// log2(e)/sqrt(32) -- folded into Q so S-MFMA output is the exp2 argument
#define QSCALE 0.2550348637f

// pack two fp32 into one dword of bf16s (truncation): lo16=bf16(lo), hi16=bf16(hi)
__device__ __forceinline__ unsigned packbf(float hi, float lo) {
    return __builtin_amdgcn_perm(__float_as_uint(hi), __float_as_uint(lo), 0x07060302u);
}

// ---------------------------------------------------------------------------
// K1 (fused): blocks 0..4095   : lf_pe  = local_feat + pos_enc(32x32) -> bf16
//             blocks 4096..8191: gf_pe  = transpose(global_feat) + pos_enc(64x64)
//             blocks 8192..9215: weights -> bf16 (Wq|Wk|Wv|Wo)
// ---------------------------------------------------------------------------
__global__ __launch_bounds__(256) void prep(const float* __restrict__ lf,
                                            const float* __restrict__ gfeat,
                                            const float* __restrict__ wq,
                                            const float* __restrict__ wk,
                                            const float* __restrict__ wv,
                                            const float* __restrict__ wo,
                                            __hip_bfloat16* __restrict__ lf_pe_b,
                                            __hip_bfloat16* __restrict__ gf_pe_b,
                                            __hip_bfloat16* __restrict__ W4) {
    __shared__ float tile[32][33];
    int b = blockIdx.x, tid = threadIdx.x;
    if (b < 4096) {
        int idx = b * 256 + tid;
        int c = idx & 255, p = (idx >> 8) & 1023;
        float div = __expf((float)(c & ~1) * PE_FACT);
        float pe = (c & 1) ? __cosf((float)(p >> 5) * (1.0f / 31.0f) * div)
                           : __sinf((float)(p & 31) * (1.0f / 31.0f) * div);
        lf_pe_b[idx] = __float2bfloat16(lf[idx] + pe);
    } else if (b < 8192) {
        int t = b - 4096;
        int n = t >> 10, r = t & 1023;
        int p0 = (r >> 3) * 32, c0 = (r & 7) * 32;
        int tx = tid & 31, ty = tid >> 5;           // 32 x 8, 4 rows each
#pragma unroll
        for (int i = 0; i < 4; ++i)
            tile[ty + 8 * i][tx] = gfeat[((size_t)n * DD + (c0 + ty + 8 * i)) * HWW + p0 + tx];
        __syncthreads();
#pragma unroll
        for (int i = 0; i < 4; ++i) {
            int p = p0 + ty + 8 * i, c = c0 + tx;
            float div = __expf((float)(c & ~1) * PE_FACT);
            float pe = (c & 1) ? __cosf((float)(p >> 6) * (1.0f / 63.0f) * div)
                               : __sinf((float)(p & 63) * (1.0f / 63.0f) * div);
            gf_pe_b[((size_t)n * HWW + p) * DD + c] = __float2bfloat16(tile[tx][ty + 8 * i] + pe);
        }
    } else {
        int idx = (b - 8192) * 256 + tid;           // < 4*65536
        int m = idx >> 16, r = idx & 65535;
        const float* src = (m == 0) ? wq : (m == 1) ? wk : (m == 2) ? wv : wo;
        W4[idx] = __float2bfloat16(src[r]);
    }
}

// ---------------------------------------------------------------------------
// K2: W-STATIONARY fused Q/K/V GEMM, software-pipelined across the 2 m-tiles.
//   Each block preloads its 64-column W fragment set (32 x s8v) once, then
//   issues BOTH m-tiles' A-loads before the first MFMA block so tile-1 loads
//   are in flight during tile-0 compute and tile-0 stores overlap tile-1 MFMAs.
//   blocks 0..127    : Q  -> bf16 (n,h,NP,32)*QSCALE
//   blocks 128..1151 : K -> (n,h,HW,32); V -> (n,h,32,VTROW) sigma-transposed
// ---------------------------------------------------------------------------
__global__ __launch_bounds__(256, 2) void gemmQKV(const __hip_bfloat16* __restrict__ Aq,
                                                  const __hip_bfloat16* __restrict__ Akv,
                                                  const __hip_bfloat16* __restrict__ W4,
                                                  const float* __restrict__ bq,
                                                  const float* __restrict__ bk,
                                                  const float* __restrict__ bv,
                                                  __hip_bfloat16* __restrict__ Qb,
                                                  __hip_bfloat16* __restrict__ Kb,
                                                  __hip_bfloat16* __restrict__ Vtb) {
    __shared__ __align__(16) unsigned stv[64][36];
    int tid = threadIdx.x;
    int wave = tid >> 6, lane = tid & 63;
    int quad = lane >> 4, c16 = lane & 15;
    int b = blockIdx.x;

    int typ, c0, mgrp, mstride;
    const short* Ap;
    const short* Wp;
    const float* bias;
    if (b < 128) {               // Q
        typ = 0; c0 = (b >> 5) * 64; mgrp = b & 31; mstride = 2048;
        Ap = (const short*)Aq; Wp = (const short*)W4; bias = bq;
    } else {                     // K or V
        int bb = b - 128;
        int combo = bb >> 7;     // 0..7
        mgrp = bb & 127; mstride = 8192;
        int mat = combo & 1;
        typ = 1 + mat;
        c0 = (combo >> 1) * 64;
        Ap = (const short*)Akv;
        Wp = (const short*)W4 + (1 + mat) * DD * DD;
        bias = mat ? bv : bk;
    }

    // ---- preload W fragments (32 x s8v = 128 VGPR) + bias ----
    s8v w[8][4];
    const short* wp0 = Wp + (c0 + c16) * DD + quad * 8;
#pragma unroll
    for (int ks = 0; ks < 8; ++ks)
#pragma unroll
        for (int t = 0; t < 4; ++t)
            w[ks][t] = *(const s8v*)(wp0 + t * 16 * DD + ks * 32);
    float bvv[4];
#pragma unroll
    for (int t = 0; t < 4; ++t) bvv[t] = bias[c0 + t * 16 + c16];

    // ---- both m-tiles' A fragments issued up front (pipelined) ----
    int mbase0 = mgrp * 64;
    int mbase1 = mbase0 + mstride;
    const short* ap0 = Ap + (mbase0 + wave * 16 + c16) * DD + quad * 8;
    const short* ap1 = Ap + (mbase1 + wave * 16 + c16) * DD + quad * 8;
    s8v a0[8], a1[8];
#pragma unroll
    for (int ks = 0; ks < 8; ++ks) a0[ks] = *(const s8v*)(ap0 + ks * 32);
#pragma unroll
    for (int ks = 0; ks < 8; ++ks) a1[ks] = *(const s8v*)(ap1 + ks * 32);

#pragma unroll
    for (int it = 0; it < 2; ++it) {
        int mbase = it ? mbase1 : mbase0;
        int m0 = mbase + wave * 16;
        f4v acc[4];
#pragma unroll
        for (int t = 0; t < 4; ++t) acc[t] = (f4v){0.f, 0.f, 0.f, 0.f};
#pragma unroll
        for (int ks = 0; ks < 8; ++ks) {
            s8v a = it ? a1[ks] : a0[ks];
#pragma unroll
            for (int t = 0; t < 4; ++t)
                acc[t] = MFMA_BF16(a, w[ks][t], acc[t], 0, 0, 0);
        }

        if (typ == 0) {          // ---- Q store ----
#pragma unroll
            for (int t = 0; t < 4; ++t) {
                int col = c0 + t * 16 + c16;
                int h = col >> 5, dh = col & 31;
#pragma unroll
                for (int r = 0; r < 4; ++r) {
                    int row = m0 + quad * 4 + r;
                    int n = row >> 10, p = row & 1023;
                    Qb[(((size_t)(n * NHEAD + h) << 10) + p) * DHD + dh] =
                        __float2bfloat16((acc[t][r] + bvv[t]) * QSCALE);
                }
            }
        } else if (typ == 1) {   // ---- K store ----
#pragma unroll
            for (int t = 0; t < 4; ++t) {
                int col = c0 + t * 16 + c16;
                int h = col >> 5, dh = col & 31;
#pragma unroll
                for (int r = 0; r < 4; ++r) {
                    int row = m0 + quad * 4 + r;
                    int n = row >> 12, p = row & 4095;
                    Kb[(((size_t)(n * NHEAD + h) << 12) + p) * DHD + dh] =
                        __float2bfloat16(acc[t][r] + bvv[t]);
                }
            }
        } else {                 // ---- V: sigma-permuted transpose bounce ----
            __syncthreads();     // protect stv from previous iteration's readers
#pragma unroll
            for (int t = 0; t < 4; ++t) {
#pragma unroll
                for (int rp = 0; rp < 2; ++rp) {
                    __hip_bfloat16 lo = __float2bfloat16(acc[t][2 * rp] + bvv[t]);
                    __hip_bfloat16 hi = __float2bfloat16(acc[t][2 * rp + 1] + bvv[t]);
                    unsigned dw = (unsigned)*(unsigned short*)&lo |
                                  ((unsigned)*(unsigned short*)&hi << 16);
                    stv[t * 16 + c16][wave * 8 + quad * 2 + rp] = dw;
                }
            }
            __syncthreads();
            int col = tid >> 2;              // 0..63
            int kd  = (tid & 3) * 8;         // out dword base (0,8,16,24)
            int grp = kd & 16;
            int ob  = kd & 15;
            unsigned vals[8];
#pragma unroll
            for (int i = 0; i < 8; ++i) {
                int o = ob + i;
                int idw = ((o >> 2) << 1) | (o & 1) | ((o & 2) << 2);  // inverse sigma
                vals[i] = stv[col][grp + idw];
            }
            int nblk = mbase >> 12;
            int kb   = mbase & 4095;
            int gh = (c0 + col) >> 5, gdh = (c0 + col) & 31;
            short* vp = (short*)Vtb + ((size_t)(nblk * NHEAD + gh) * DHD + gdh) * VTROW + kb + kd * 2;
            *(u4v*)(vp)     = (u4v){vals[0], vals[1], vals[2], vals[3]};
            *(u4v*)(vp + 8) = (u4v){vals[4], vals[5], vals[6], vals[7]};
        }
    }
}

// ---------------------------------------------------------------------------
// K3: attention partial. NO LDS, no cross-lane. 64 q-rows/wave.
//   S^T = K.Q^T -> exp2 -> in-lane pack (keys sigma-ordered) -> O^T = V^T.P^T.
//   grid: flat 128*NC, XCD-swizzled; writes bf16 O-partials + fp32 row-sums.
// ---------------------------------------------------------------------------
template <int NC>
__global__ __launch_bounds__(256) void attn(const __hip_bfloat16* __restrict__ Q,
                                            const __hip_bfloat16* __restrict__ Kg,
                                            const __hip_bfloat16* __restrict__ Vt,
                                            __hip_bfloat16* __restrict__ Opart,
                                            float* __restrict__ lpart) {
    constexpr int CK = HWW / NC;         // keys per chunk
    constexpr int NSTEP = CK / 32;

    int tid = threadIdx.x;
    int wave = tid >> 6, lane = tid & 63;
    int quad = lane >> 4, c16 = lane & 15;

    int id = blockIdx.x;
    int xcd = id & 7;
    int s = id >> 3;
    int qtile = s & 3;
    int gidx = ((s >> 2) << 3) | xcd;    // 0..32*NC-1
    int bh = gidx & 31;
    int chunk = gidx >> 5;

    int q0 = qtile * 256 + wave * 64;

    const short* Qs = (const short*)Q + (size_t)bh * NPTS * DHD;
    const short* Ks = (const short*)Kg + ((size_t)bh * HWW + (size_t)chunk * CK) * DHD;
    const short* Vs = (const short*)Vt + (size_t)bh * DHD * VTROW + (size_t)chunk * CK;

    s8v aq[4];
#pragma unroll
    for (int g = 0; g < 4; ++g)
        aq[g] = *(const s8v*)(Qs + (q0 + g * 16 + c16) * DHD + quad * 8);

    const f4v zf = {0.f, 0.f, 0.f, 0.f};
    f4v o[4][2];
#pragma unroll
    for (int g = 0; g < 4; ++g) { o[g][0] = zf; o[g][1] = zf; }
    float lsum[4] = {0.f, 0.f, 0.f, 0.f};

    const short* kbase  = Ks + c16 * DHD + quad * 8;
    const short* v0base = Vs + c16 * VTROW + quad * 8;
    const short* v1base = Vs + (16 + c16) * VTROW + quad * 8;

    s8v kfA = *(const s8v*)(kbase);
    s8v kfB = *(const s8v*)(kbase + 16 * DHD);
    s8v vfA = *(const s8v*)(v0base);
    s8v vfB = *(const s8v*)(v1base);

    for (int st = 0; st < NSTEP; ++st) {
        bool more = (st + 1) < NSTEP;
        s8v nkA, nkB, nvA, nvB;
        if (more) {
            int ko = (st + 1) * 32;
            nkA = *(const s8v*)(kbase + ko * DHD);
            nkB = *(const s8v*)(kbase + ko * DHD + 16 * DHD);
            nvA = *(const s8v*)(v0base + ko);
            nvB = *(const s8v*)(v1base + ko);
        }
#pragma unroll
        for (int g = 0; g < 4; ++g) {
            f4v sA = MFMA_BF16(kfA, aq[g], zf, 0, 0, 0);   // P^T keys 4q+r
            f4v sB = MFMA_BF16(kfB, aq[g], zf, 0, 0, 0);   // P^T keys 16+4q+r
            float pA0 = __builtin_amdgcn_exp2f(sA[0]);
            float pA1 = __builtin_amdgcn_exp2f(sA[1]);
            float pA2 = __builtin_amdgcn_exp2f(sA[2]);
            float pA3 = __builtin_amdgcn_exp2f(sA[3]);
            float pB0 = __builtin_amdgcn_exp2f(sB[0]);
            float pB1 = __builtin_amdgcn_exp2f(sB[1]);
            float pB2 = __builtin_amdgcn_exp2f(sB[2]);
            float pB3 = __builtin_amdgcn_exp2f(sB[3]);
            lsum[g] += ((pA0 + pA1) + (pA2 + pA3)) + ((pB0 + pB1) + (pB2 + pB3));
            // B-frag directly (V^T is sigma-ordered): k=8q+j <-> {sA r0..3, sB r0..3}
            union { u4v u; s8v s; } pf;
            pf.u = (u4v){packbf(pA1, pA0), packbf(pA3, pA2),
                         packbf(pB1, pB0), packbf(pB3, pB2)};
            o[g][0] = MFMA_BF16(vfA, pf.s, o[g][0], 0, 0, 0);  // dh 0..15
            o[g][1] = MFMA_BF16(vfB, pf.s, o[g][1], 0, 0, 0);  // dh 16..31
        }
        if (more) { kfA = nkA; kfB = nkB; vfA = nvA; vfB = nvB; }
    }

    // epilogue: O^T lane holds dh=16*half+4quad+r, q=q0+g*16+c16
    size_t obase = (size_t)(chunk * 32 + bh) * NPTS;
#pragma unroll
    for (int g = 0; g < 4; ++g) {
        float l = lsum[g];
        l += __shfl_xor(l, 16);
        l += __shfl_xor(l, 32);
        int q = q0 + g * 16 + c16;
        if (quad == 0) lpart[obase + q] = l;
        unsigned d0 = packbf(o[g][0][1], o[g][0][0]);
        unsigned d1 = packbf(o[g][0][3], o[g][0][2]);
        unsigned d2 = packbf(o[g][1][1], o[g][1][0]);
        unsigned d3 = packbf(o[g][1][3], o[g][1][2]);
        unsigned* op = (unsigned*)Opart + (obase + q) * (DHD / 2);
        *(u2v*)(op + 2 * quad)     = (u2v){d0, d1};
        *(u2v*)(op + 8 + 2 * quad) = (u2v){d2, d3};
    }
}

// ---------------------------------------------------------------------------
// K4 (fused): combine chunks into AL tile in LDS, then output GEMM.
//   grid 256 blocks x 16 rows (1 block/CU). AL = (sum O)/(sum l) + lf_pe;
//   out = AL @ Wo^T + bo (fp32).
// ---------------------------------------------------------------------------
template <int NC>
__global__ __launch_bounds__(256) void combineO(const __hip_bfloat16* __restrict__ Opart,
                                                const float* __restrict__ lpart,
                                                const __hip_bfloat16* __restrict__ lf_pe,
                                                const __hip_bfloat16* __restrict__ Wo4,
                                                const float* __restrict__ bo,
                                                float* __restrict__ out) {
    __shared__ __align__(16) short al[16][264];
    int tid = threadIdx.x;
    int m0 = blockIdx.x * 16;
    {   // phase 1: combine -> AL (bf16) in LDS. thread = (row, one 16-col seg)
        int rl  = tid >> 4;           // 0..15
        int seg = tid & 15;           // 16 cols each
        int h   = seg >> 1;
        int rg = m0 + rl;
        int n = rg >> 10, q = rg & 1023;
        size_t bhq = ((size_t)(n * NHEAD + h) << 10) + q;
        int dh0 = (seg & 1) * 16;     // offset within the head's 32 dh
        float l = 0.f;
        float ov[16];
#pragma unroll
        for (int d = 0; d < 16; ++d) ov[d] = 0.f;
#pragma unroll
        for (int ch = 0; ch < NC; ++ch) {
            size_t base = (size_t)ch * 32 * NPTS + bhq;
            l += lpart[base];
            const unsigned* op = (const unsigned*)((const short*)Opart + base * DHD + dh0);
#pragma unroll
            for (int dw = 0; dw < 8; ++dw) {
                unsigned u = op[dw];
                ov[2 * dw]     += __uint_as_float(u << 16);
                ov[2 * dw + 1] += __uint_as_float(u & 0xffff0000u);
            }
        }
        float linv = 1.0f / l;
        const unsigned* lp = (const unsigned*)((const short*)lf_pe + ((size_t)rg * DD + seg * 16));
        unsigned* dst = (unsigned*)&al[rl][seg * 16];
#pragma unroll
        for (int dw = 0; dw < 8; ++dw) {
            unsigned u = lp[dw];
            float x0 = ov[2 * dw] * linv     + __uint_as_float(u << 16);
            float x1 = ov[2 * dw + 1] * linv + __uint_as_float(u & 0xffff0000u);
            dst[dw] = packbf(x1, x0);
        }
    }
    __syncthreads();
    // phase 2: GEMM AL(16x256) @ Wo^T -> out rows m0..m0+15 (fp32)
    int wave = tid >> 6, lane = tid & 63;
    int quad = lane >> 4, c16 = lane & 15;
    int ch0 = wave * 64;
    f4v acc[4];
#pragma unroll
    for (int t = 0; t < 4; ++t) acc[t] = (f4v){0.f, 0.f, 0.f, 0.f};
#pragma unroll
    for (int ks = 0; ks < 8; ++ks) {
        s8v af = *(const s8v*)&al[c16][ks * 32 + quad * 8];
#pragma unroll
        for (int t = 0; t < 4; ++t) {
            const short* wp = (const short*)Wo4 + (ch0 + t * 16 + c16) * DD + ks * 32 + quad * 8;
            s8v bf = *(const s8v*)wp;
            acc[t] = MFMA_BF16(af, bf, acc[t], 0, 0, 0);
        }
    }
#pragma unroll
    for (int t = 0; t < 4; ++t) {
        int col = ch0 + t * 16 + c16;
        float bv = bo[col];
#pragma unroll
        for (int r = 0; r < 4; ++r) {
            int row = m0 + quad * 4 + r;
            out[(size_t)row * DD + col] = acc[t][r] + bv;
        }
    }
}

// ---------------------------------------------------------------------------
extern "C" void kernel_launch(void* const* d_in, const int* in_sizes, int n_in,
                              void* d_out, int out_size, void* d_ws, size_t ws_size,
                              hipStream_t stream) {
    const float* lf    = (const float*)d_in[0];
    const float* gfeat = (const float*)d_in[1];
    const float* Wq    = (const float*)d_in[2];
    const float* bq    = (const float*)d_in[3];
    const float* Wk    = (const float*)d_in[4];
    const float* bk    = (const float*)d_in[5];
    const float* Wv    = (const float*)d_in[6];
    const float* bv    = (const float*)d_in[7];
    const float* Wo    = (const float*)d_in[8];
    const float* bo    = (const float*)d_in[9];

    const size_t MB = 1u << 20;
    char* ws = (char*)d_ws;
    __hip_bfloat16* lf_pe_b = (__hip_bfloat16*)(ws);                          // 0..2 MB
    __hip_bfloat16* gf_pe_b = (__hip_bfloat16*)(ws + 2 * MB);                 // 2..10 MB
    __hip_bfloat16* W4      = (__hip_bfloat16*)(ws + 10 * MB);                // 10..10.5 MB
    __hip_bfloat16* Qb      = (__hip_bfloat16*)(ws + 10 * MB + 512 * 1024);   // 10.5..12.5
    __hip_bfloat16* Kb      = (__hip_bfloat16*)(ws + 12 * MB + 512 * 1024);   // 12.5..20.5
    __hip_bfloat16* Vtb     = (__hip_bfloat16*)(ws + 20 * MB + 512 * 1024);   // 20.5..29
    float*          lpart   = (float*)(ws + 31 * MB);                         // 31..32 MB
    __hip_bfloat16* Opart   = (__hip_bfloat16*)(ws + 32 * MB);                // 32..32+NC*2 MB

    prep<<<dim3(9216), dim3(256), 0, stream>>>(lf, gfeat, Wq, Wk, Wv, Wo,
                                               lf_pe_b, gf_pe_b, W4);
    gemmQKV<<<dim3(1152), dim3(256), 0, stream>>>(lf_pe_b, gf_pe_b, W4, bq, bk, bv,
                                                  Qb, Kb, Vtb);

    if (ws_size >= 48 * MB) {
        attn<8><<<dim3(128 * 8), dim3(256), 0, stream>>>(Qb, Kb, Vtb, Opart, lpart);
        combineO<8><<<dim3(256), dim3(256), 0, stream>>>(Opart, lpart, lf_pe_b,
                                                         W4 + 3 * DD * DD, bo, (float*)d_out);
    } else if (ws_size >= 40 * MB) {
        attn<4><<<dim3(128 * 4), dim3(256), 0, stream>>>(Qb, Kb, Vtb, Opart, lpart);
        combineO<4><<<dim3(256), dim3(256), 0, stream>>>(Opart, lpart, lf_pe_b,
                                                         W4 + 3 * DD * DD, bo, (float*)d_out);
    } else if (ws_size >= 36 * MB) {
        attn<2><<<dim3(128 * 2), dim3(256), 0, stream>>>(Qb, Kb, Vtb, Opart, lpart);
        combineO<2><<<dim3(256), dim3(256), 0, stream>>>(Opart, lpart, lf_pe_b,
                                                         W4 + 3 * DD * DD, bo, (float*)d_out);
    } else {
        attn<1><<<dim3(128 * 1), dim3(256), 0, stream>>>(Qb, Kb, Vtb, Opart, lpart);
        combineO<1><<<dim3(256), dim3(256), 0, stream>>>(Opart, lpart, lf_pe_b,
                                                         W4 + 3 * DD * DD, bo, (float*)d_out);
    }
}

// Round 8
// 159.511 us; speedup vs baseline: 1.2930x; 1.0138x over previous
//
#include <hip/hip_runtime.h>
#include <hip/hip_bf16.h>
#include <math.h>

// Problem constants
#define NB    4
#define NPTS  1024
#define DD    256
#define HWW   4096
#define NHEAD 8
#define DHD   32
#define VTROW 4128   // padded V^T row length in shorts (4096 + 32)

typedef short s8v  __attribute__((ext_vector_type(8)));   // 8 x bf16 bits
typedef float f4v  __attribute__((ext_vector_type(4)));
typedef unsigned int u2v __attribute__((ext_vector_type(2)));
typedef unsigned int u4v __attribute__((ext_vector_type(4)));

#define MFMA_BF16 __builtin_amdgcn_mfma_f32_16x16x32_bf16

// -log(10000)/256
#define PE_FACT (-9.210340371976184f / 256.0f)
// log2(e)/sqrt(32) -- folded into Q so S-MFMA output is the exp2 argument
#define QSCALE 0.2550348637f

// pack two fp32 into one dword of bf16s (truncation): lo16=bf16(lo), hi16=bf16(hi)
__device__ __forceinline__ unsigned packbf(float hi, float lo) {
    return __builtin_amdgcn_perm(__float_as_uint(hi), __float_as_uint(lo), 0x07060302u);
}

// ---------------------------------------------------------------------------
// K1 (fused): blocks 0..4095   : lf_pe  = local_feat + pos_enc(32x32) -> bf16
//             blocks 4096..8191: gf_pe  = transpose(global_feat) + pos_enc(64x64)
//             blocks 8192..9215: weights -> bf16 (Wq|Wk|Wv|Wo)
// ---------------------------------------------------------------------------
__global__ __launch_bounds__(256) void prep(const float* __restrict__ lf,
                                            const float* __restrict__ gfeat,
                                            const float* __restrict__ wq,
                                            const float* __restrict__ wk,
                                            const float* __restrict__ wv,
                                            const float* __restrict__ wo,
                                            __hip_bfloat16* __restrict__ lf_pe_b,
                                            __hip_bfloat16* __restrict__ gf_pe_b,
                                            __hip_bfloat16* __restrict__ W4) {
    __shared__ float tile[32][33];
    int b = blockIdx.x, tid = threadIdx.x;
    if (b < 4096) {
        int idx = b * 256 + tid;
        int c = idx & 255, p = (idx >> 8) & 1023;
        float div = __expf((float)(c & ~1) * PE_FACT);
        float pe = (c & 1) ? __cosf((float)(p >> 5) * (1.0f / 31.0f) * div)
                           : __sinf((float)(p & 31) * (1.0f / 31.0f) * div);
        lf_pe_b[idx] = __float2bfloat16(lf[idx] + pe);
    } else if (b < 8192) {
        int t = b - 4096;
        int n = t >> 10, r = t & 1023;
        int p0 = (r >> 3) * 32, c0 = (r & 7) * 32;
        int tx = tid & 31, ty = tid >> 5;           // 32 x 8, 4 rows each
#pragma unroll
        for (int i = 0; i < 4; ++i)
            tile[ty + 8 * i][tx] = gfeat[((size_t)n * DD + (c0 + ty + 8 * i)) * HWW + p0 + tx];
        __syncthreads();
#pragma unroll
        for (int i = 0; i < 4; ++i) {
            int p = p0 + ty + 8 * i, c = c0 + tx;
            float div = __expf((float)(c & ~1) * PE_FACT);
            float pe = (c & 1) ? __cosf((float)(p >> 6) * (1.0f / 63.0f) * div)
                               : __sinf((float)(p & 63) * (1.0f / 63.0f) * div);
            gf_pe_b[((size_t)n * HWW + p) * DD + c] = __float2bfloat16(tile[tx][ty + 8 * i] + pe);
        }
    } else {
        int idx = (b - 8192) * 256 + tid;           // < 4*65536
        int m = idx >> 16, r = idx & 65535;
        const float* src = (m == 0) ? wq : (m == 1) ? wk : (m == 2) ? wv : wo;
        W4[idx] = __float2bfloat16(src[r]);
    }
}

// ---------------------------------------------------------------------------
// K2: W-STATIONARY fused Q/K/V GEMM, pipelined over 2 m-tiles, with
//   ALL stores LDS-bounced to coalesced 16B (Q/K were 2-byte scatters before:
//   64 L2 txns per store instr -> silent ~90%-idle stall; V was already fixed).
//   blocks 0..127    : Q  -> bf16 (n,h,NP,32)*QSCALE
//   blocks 128..1151 : K -> (n,h,HW,32); V -> (n,h,32,VTROW) sigma-transposed
// ---------------------------------------------------------------------------
__global__ __launch_bounds__(256, 2) void gemmQKV(const __hip_bfloat16* __restrict__ Aq,
                                                  const __hip_bfloat16* __restrict__ Akv,
                                                  const __hip_bfloat16* __restrict__ W4,
                                                  const float* __restrict__ bq,
                                                  const float* __restrict__ bk,
                                                  const float* __restrict__ bv,
                                                  __hip_bfloat16* __restrict__ Qb,
                                                  __hip_bfloat16* __restrict__ Kb,
                                                  __hip_bfloat16* __restrict__ Vtb) {
    __shared__ __align__(16) unsigned shbuf[2304];   // 9216 B, dual-purpose
    int tid = threadIdx.x;
    int wave = tid >> 6, lane = tid & 63;
    int quad = lane >> 4, c16 = lane & 15;
    int b = blockIdx.x;

    int typ, c0, mgrp, mstride;
    const short* Ap;
    const short* Wp;
    const float* bias;
    if (b < 128) {               // Q
        typ = 0; c0 = (b >> 5) * 64; mgrp = b & 31; mstride = 2048;
        Ap = (const short*)Aq; Wp = (const short*)W4; bias = bq;
    } else {                     // K or V
        int bb = b - 128;
        int combo = bb >> 7;     // 0..7
        mgrp = bb & 127; mstride = 8192;
        int mat = combo & 1;
        typ = 1 + mat;
        c0 = (combo >> 1) * 64;
        Ap = (const short*)Akv;
        Wp = (const short*)W4 + (1 + mat) * DD * DD;
        bias = mat ? bv : bk;
    }

    // ---- preload W fragments (32 x s8v = 128 VGPR) + bias ----
    s8v w[8][4];
    const short* wp0 = Wp + (c0 + c16) * DD + quad * 8;
#pragma unroll
    for (int ks = 0; ks < 8; ++ks)
#pragma unroll
        for (int t = 0; t < 4; ++t)
            w[ks][t] = *(const s8v*)(wp0 + t * 16 * DD + ks * 32);
    float bvv[4];
#pragma unroll
    for (int t = 0; t < 4; ++t) bvv[t] = bias[c0 + t * 16 + c16];

    // ---- both m-tiles' A fragments issued up front (pipelined) ----
    int mbase0 = mgrp * 64;
    int mbase1 = mbase0 + mstride;
    const short* ap0 = Ap + (mbase0 + wave * 16 + c16) * DD + quad * 8;
    const short* ap1 = Ap + (mbase1 + wave * 16 + c16) * DD + quad * 8;
    s8v a0[8], a1[8];
#pragma unroll
    for (int ks = 0; ks < 8; ++ks) a0[ks] = *(const s8v*)(ap0 + ks * 32);
#pragma unroll
    for (int ks = 0; ks < 8; ++ks) a1[ks] = *(const s8v*)(ap1 + ks * 32);

#pragma unroll
    for (int it = 0; it < 2; ++it) {
        int mbase = it ? mbase1 : mbase0;
        f4v acc[4];
#pragma unroll
        for (int t = 0; t < 4; ++t) acc[t] = (f4v){0.f, 0.f, 0.f, 0.f};
#pragma unroll
        for (int ks = 0; ks < 8; ++ks) {
            s8v a = it ? a1[ks] : a0[ks];
#pragma unroll
            for (int t = 0; t < 4; ++t)
                acc[t] = MFMA_BF16(a, w[ks][t], acc[t], 0, 0, 0);
        }

        if (typ != 2) {          // ---- Q / K: transpose bounce, coalesced store ----
            short* kt = (short*)shbuf;           // [64 rows][72 shorts] (64 + 8 pad)
            __syncthreads();     // prior iteration's readers done
#pragma unroll
            for (int t = 0; t < 4; ++t) {
#pragma unroll
                for (int r = 0; r < 4; ++r) {
                    float v = acc[t][r] + bvv[t];
                    if (typ == 0) v *= QSCALE;
                    __hip_bfloat16 hv = __float2bfloat16(v);
                    kt[(wave * 16 + quad * 4 + r) * 72 + t * 16 + c16] = *(short*)&hv;
                }
            }
            __syncthreads();
            int pl  = tid >> 2;          // local row 0..63
            int seg = tid & 3;           // 16-short (32B) segment
            const short* src = kt + pl * 72 + seg * 16;
            u4v w0 = *(const u4v*)(src);
            u4v w1 = *(const u4v*)(src + 8);
            int h   = (c0 >> 5) + (seg >> 1);
            int dh0 = (seg & 1) * 16;
            short* dst;
            if (typ == 0) {
                int row = mbase + pl;
                int n = row >> 10, p = row & 1023;
                dst = (short*)Qb + (((size_t)(n * NHEAD + h) << 10) + p) * DHD + dh0;
            } else {
                int n = mbase >> 12, p = (mbase & 4095) + pl;
                dst = (short*)Kb + (((size_t)(n * NHEAD + h) << 12) + p) * DHD + dh0;
            }
            *(u4v*)(dst)     = w0;
            *(u4v*)(dst + 8) = w1;
        } else {                 // ---- V: sigma-permuted transpose bounce ----
            unsigned (*stv)[36] = (unsigned (*)[36])shbuf;
            __syncthreads();     // protect stv from previous iteration's readers
#pragma unroll
            for (int t = 0; t < 4; ++t) {
#pragma unroll
                for (int rp = 0; rp < 2; ++rp) {
                    __hip_bfloat16 lo = __float2bfloat16(acc[t][2 * rp] + bvv[t]);
                    __hip_bfloat16 hi = __float2bfloat16(acc[t][2 * rp + 1] + bvv[t]);
                    unsigned dw = (unsigned)*(unsigned short*)&lo |
                                  ((unsigned)*(unsigned short*)&hi << 16);
                    stv[t * 16 + c16][wave * 8 + quad * 2 + rp] = dw;
                }
            }
            __syncthreads();
            int col = tid >> 2;              // 0..63
            int kd  = (tid & 3) * 8;         // out dword base (0,8,16,24)
            int grp = kd & 16;
            int ob  = kd & 15;
            unsigned vals[8];
#pragma unroll
            for (int i = 0; i < 8; ++i) {
                int o = ob + i;
                int idw = ((o >> 2) << 1) | (o & 1) | ((o & 2) << 2);  // inverse sigma
                vals[i] = stv[col][grp + idw];
            }
            int nblk = mbase >> 12;
            int kb   = mbase & 4095;
            int gh = (c0 + col) >> 5, gdh = (c0 + col) & 31;
            short* vp = (short*)Vtb + ((size_t)(nblk * NHEAD + gh) * DHD + gdh) * VTROW + kb + kd * 2;
            *(u4v*)(vp)     = (u4v){vals[0], vals[1], vals[2], vals[3]};
            *(u4v*)(vp + 8) = (u4v){vals[4], vals[5], vals[6], vals[7]};
        }
    }
}

// ---------------------------------------------------------------------------
// K3: attention partial. NO LDS, no cross-lane. 64 q-rows/wave.
//   S^T = K.Q^T -> exp2 -> in-lane pack (keys sigma-ordered) -> O^T = V^T.P^T.
//   grid: flat 128*NC, XCD-swizzled; writes bf16 O-partials + fp32 row-sums.
// ---------------------------------------------------------------------------
template <int NC>
__global__ __launch_bounds__(256) void attn(const __hip_bfloat16* __restrict__ Q,
                                            const __hip_bfloat16* __restrict__ Kg,
                                            const __hip_bfloat16* __restrict__ Vt,
                                            __hip_bfloat16* __restrict__ Opart,
                                            float* __restrict__ lpart) {
    constexpr int CK = HWW / NC;         // keys per chunk
    constexpr int NSTEP = CK / 32;

    int tid = threadIdx.x;
    int wave = tid >> 6, lane = tid & 63;
    int quad = lane >> 4, c16 = lane & 15;

    int id = blockIdx.x;
    int xcd = id & 7;
    int s = id >> 3;
    int qtile = s & 3;
    int gidx = ((s >> 2) << 3) | xcd;    // 0..32*NC-1
    int bh = gidx & 31;
    int chunk = gidx >> 5;

    int q0 = qtile * 256 + wave * 64;

    const short* Qs = (const short*)Q + (size_t)bh * NPTS * DHD;
    const short* Ks = (const short*)Kg + ((size_t)bh * HWW + (size_t)chunk * CK) * DHD;
    const short* Vs = (const short*)Vt + (size_t)bh * DHD * VTROW + (size_t)chunk * CK;

    s8v aq[4];
#pragma unroll
    for (int g = 0; g < 4; ++g)
        aq[g] = *(const s8v*)(Qs + (q0 + g * 16 + c16) * DHD + quad * 8);

    const f4v zf = {0.f, 0.f, 0.f, 0.f};
    f4v o[4][2];
#pragma unroll
    for (int g = 0; g < 4; ++g) { o[g][0] = zf; o[g][1] = zf; }
    float lsum[4] = {0.f, 0.f, 0.f, 0.f};

    const short* kbase  = Ks + c16 * DHD + quad * 8;
    const short* v0base = Vs + c16 * VTROW + quad * 8;
    const short* v1base = Vs + (16 + c16) * VTROW + quad * 8;

    s8v kfA = *(const s8v*)(kbase);
    s8v kfB = *(const s8v*)(kbase + 16 * DHD);
    s8v vfA = *(const s8v*)(v0base);
    s8v vfB = *(const s8v*)(v1base);

    for (int st = 0; st < NSTEP; ++st) {
        bool more = (st + 1) < NSTEP;
        s8v nkA, nkB, nvA, nvB;
        if (more) {
            int ko = (st + 1) * 32;
            nkA = *(const s8v*)(kbase + ko * DHD);
            nkB = *(const s8v*)(kbase + ko * DHD + 16 * DHD);
            nvA = *(const s8v*)(v0base + ko);
            nvB = *(const s8v*)(v1base + ko);
        }
#pragma unroll
        for (int g = 0; g < 4; ++g) {
            f4v sA = MFMA_BF16(kfA, aq[g], zf, 0, 0, 0);   // P^T keys 4q+r
            f4v sB = MFMA_BF16(kfB, aq[g], zf, 0, 0, 0);   // P^T keys 16+4q+r
            float pA0 = __builtin_amdgcn_exp2f(sA[0]);
            float pA1 = __builtin_amdgcn_exp2f(sA[1]);
            float pA2 = __builtin_amdgcn_exp2f(sA[2]);
            float pA3 = __builtin_amdgcn_exp2f(sA[3]);
            float pB0 = __builtin_amdgcn_exp2f(sB[0]);
            float pB1 = __builtin_amdgcn_exp2f(sB[1]);
            float pB2 = __builtin_amdgcn_exp2f(sB[2]);
            float pB3 = __builtin_amdgcn_exp2f(sB[3]);
            lsum[g] += ((pA0 + pA1) + (pA2 + pA3)) + ((pB0 + pB1) + (pB2 + pB3));
            // B-frag directly (V^T is sigma-ordered): k=8q+j <-> {sA r0..3, sB r0..3}
            union { u4v u; s8v s; } pf;
            pf.u = (u4v){packbf(pA1, pA0), packbf(pA3, pA2),
                         packbf(pB1, pB0), packbf(pB3, pB2)};
            o[g][0] = MFMA_BF16(vfA, pf.s, o[g][0], 0, 0, 0);  // dh 0..15
            o[g][1] = MFMA_BF16(vfB, pf.s, o[g][1], 0, 0, 0);  // dh 16..31
        }
        if (more) { kfA = nkA; kfB = nkB; vfA = nvA; vfB = nvB; }
    }

    // epilogue: O^T lane holds dh=16*half+4quad+r, q=q0+g*16+c16
    size_t obase = (size_t)(chunk * 32 + bh) * NPTS;
#pragma unroll
    for (int g = 0; g < 4; ++g) {
        float l = lsum[g];
        l += __shfl_xor(l, 16);
        l += __shfl_xor(l, 32);
        int q = q0 + g * 16 + c16;
        if (quad == 0) lpart[obase + q] = l;
        unsigned d0 = packbf(o[g][0][1], o[g][0][0]);
        unsigned d1 = packbf(o[g][0][3], o[g][0][2]);
        unsigned d2 = packbf(o[g][1][1], o[g][1][0]);
        unsigned d3 = packbf(o[g][1][3], o[g][1][2]);
        unsigned* op = (unsigned*)Opart + (obase + q) * (DHD / 2);
        *(u2v*)(op + 2 * quad)     = (u2v){d0, d1};
        *(u2v*)(op + 8 + 2 * quad) = (u2v){d2, d3};
    }
}

// ---------------------------------------------------------------------------
// K4 (fused): combine chunks into AL tile in LDS, then output GEMM.
//   grid 256 blocks x 16 rows (1 block/CU). AL = (sum O)/(sum l) + lf_pe;
//   out = AL @ Wo^T + bo (fp32).
// ---------------------------------------------------------------------------
template <int NC>
__global__ __launch_bounds__(256) void combineO(const __hip_bfloat16* __restrict__ Opart,
                                                const float* __restrict__ lpart,
                                                const __hip_bfloat16* __restrict__ lf_pe,
                                                const __hip_bfloat16* __restrict__ Wo4,
                                                const float* __restrict__ bo,
                                                float* __restrict__ out) {
    __shared__ __align__(16) short al[16][264];
    int tid = threadIdx.x;
    int m0 = blockIdx.x * 16;
    {   // phase 1: combine -> AL (bf16) in LDS. thread = (row, one 16-col seg)
        int rl  = tid >> 4;           // 0..15
        int seg = tid & 15;           // 16 cols each
        int h   = seg >> 1;
        int rg = m0 + rl;
        int n = rg >> 10, q = rg & 1023;
        size_t bhq = ((size_t)(n * NHEAD + h) << 10) + q;
        int dh0 = (seg & 1) * 16;     // offset within the head's 32 dh
        float l = 0.f;
        float ov[16];
#pragma unroll
        for (int d = 0; d < 16; ++d) ov[d] = 0.f;
#pragma unroll
        for (int ch = 0; ch < NC; ++ch) {
            size_t base = (size_t)ch * 32 * NPTS + bhq;
            l += lpart[base];
            const unsigned* op = (const unsigned*)((const short*)Opart + base * DHD + dh0);
#pragma unroll
            for (int dw = 0; dw < 8; ++dw) {
                unsigned u = op[dw];
                ov[2 * dw]     += __uint_as_float(u << 16);
                ov[2 * dw + 1] += __uint_as_float(u & 0xffff0000u);
            }
        }
        float linv = 1.0f / l;
        const unsigned* lp = (const unsigned*)((const short*)lf_pe + ((size_t)rg * DD + seg * 16));
        unsigned* dst = (unsigned*)&al[rl][seg * 16];
#pragma unroll
        for (int dw = 0; dw < 8; ++dw) {
            unsigned u = lp[dw];
            float x0 = ov[2 * dw] * linv     + __uint_as_float(u << 16);
            float x1 = ov[2 * dw + 1] * linv + __uint_as_float(u & 0xffff0000u);
            dst[dw] = packbf(x1, x0);
        }
    }
    __syncthreads();
    // phase 2: GEMM AL(16x256) @ Wo^T -> out rows m0..m0+15 (fp32)
    int wave = tid >> 6, lane = tid & 63;
    int quad = lane >> 4, c16 = lane & 15;
    int ch0 = wave * 64;
    f4v acc[4];
#pragma unroll
    for (int t = 0; t < 4; ++t) acc[t] = (f4v){0.f, 0.f, 0.f, 0.f};
#pragma unroll
    for (int ks = 0; ks < 8; ++ks) {
        s8v af = *(const s8v*)&al[c16][ks * 32 + quad * 8];
#pragma unroll
        for (int t = 0; t < 4; ++t) {
            const short* wp = (const short*)Wo4 + (ch0 + t * 16 + c16) * DD + ks * 32 + quad * 8;
            s8v bf = *(const s8v*)wp;
            acc[t] = MFMA_BF16(af, bf, acc[t], 0, 0, 0);
        }
    }
#pragma unroll
    for (int t = 0; t < 4; ++t) {
        int col = ch0 + t * 16 + c16;
        float bv = bo[col];
#pragma unroll
        for (int r = 0; r < 4; ++r) {
            int row = m0 + quad * 4 + r;
            out[(size_t)row * DD + col] = acc[t][r] + bv;
        }
    }
}

// ---------------------------------------------------------------------------
extern "C" void kernel_launch(void* const* d_in, const int* in_sizes, int n_in,
                              void* d_out, int out_size, void* d_ws, size_t ws_size,
                              hipStream_t stream) {
    const float* lf    = (const float*)d_in[0];
    const float* gfeat = (const float*)d_in[1];
    const float* Wq    = (const float*)d_in[2];
    const float* bq    = (const float*)d_in[3];
    const float* Wk    = (const float*)d_in[4];
    const float* bk    = (const float*)d_in[5];
    const float* Wv    = (const float*)d_in[6];
    const float* bv    = (const float*)d_in[7];
    const float* Wo    = (const float*)d_in[8];
    const float* bo    = (const float*)d_in[9];

    const size_t MB = 1u << 20;
    char* ws = (char*)d_ws;
    __hip_bfloat16* lf_pe_b = (__hip_bfloat16*)(ws);                          // 0..2 MB
    __hip_bfloat16* gf_pe_b = (__hip_bfloat16*)(ws + 2 * MB);                 // 2..10 MB
    __hip_bfloat16* W4      = (__hip_bfloat16*)(ws + 10 * MB);                // 10..10.5 MB
    __hip_bfloat16* Qb      = (__hip_bfloat16*)(ws + 10 * MB + 512 * 1024);   // 10.5..12.5
    __hip_bfloat16* Kb      = (__hip_bfloat16*)(ws + 12 * MB + 512 * 1024);   // 12.5..20.5
    __hip_bfloat16* Vtb     = (__hip_bfloat16*)(ws + 20 * MB + 512 * 1024);   // 20.5..29
    float*          lpart   = (float*)(ws + 31 * MB);                         // 31..32 MB
    __hip_bfloat16* Opart   = (__hip_bfloat16*)(ws + 32 * MB);                // 32..32+NC*2 MB

    prep<<<dim3(9216), dim3(256), 0, stream>>>(lf, gfeat, Wq, Wk, Wv, Wo,
                                               lf_pe_b, gf_pe_b, W4);
    gemmQKV<<<dim3(1152), dim3(256), 0, stream>>>(lf_pe_b, gf_pe_b, W4, bq, bk, bv,
                                                  Qb, Kb, Vtb);

    if (ws_size >= 48 * MB) {
        attn<8><<<dim3(128 * 8), dim3(256), 0, stream>>>(Qb, Kb, Vtb, Opart, lpart);
        combineO<8><<<dim3(256), dim3(256), 0, stream>>>(Opart, lpart, lf_pe_b,
                                                         W4 + 3 * DD * DD, bo, (float*)d_out);
    } else if (ws_size >= 40 * MB) {
        attn<4><<<dim3(128 * 4), dim3(256), 0, stream>>>(Qb, Kb, Vtb, Opart, lpart);
        combineO<4><<<dim3(256), dim3(256), 0, stream>>>(Opart, lpart, lf_pe_b,
                                                         W4 + 3 * DD * DD, bo, (float*)d_out);
    } else if (ws_size >= 36 * MB) {
        attn<2><<<dim3(128 * 2), dim3(256), 0, stream>>>(Qb, Kb, Vtb, Opart, lpart);
        combineO<2><<<dim3(256), dim3(256), 0, stream>>>(Opart, lpart, lf_pe_b,
                                                         W4 + 3 * DD * DD, bo, (float*)d_out);
    } else {
        attn<1><<<dim3(128 * 1), dim3(256), 0, stream>>>(Qb, Kb, Vtb, Opart, lpart);
        combineO<1><<<dim3(256), dim3(256), 0, stream>>>(Opart, lpart, lf_pe_b,
                                                         W4 + 3 * DD * DD, bo, (float*)d_out);
    }
}